// Round 8
// baseline (39363.541 us; speedup 1.0000x reference)
//
#include <hip/hip_runtime.h>
#include <hip/hip_bf16.h>

// Sizes from the reference
#define T_   4096
#define E_   8

typedef unsigned long long ull;

__device__ __forceinline__ float sigm(float x)  { return 1.0f / (1.0f + __expf(-x)); }
__device__ __forceinline__ float tanh_(float x) { return 1.0f - 2.0f / (__expf(2.0f * x) + 1.0f); }

__device__ __forceinline__ ull aload64(const ull* p) {
  return __hip_atomic_load(p, __ATOMIC_RELAXED, __HIP_MEMORY_SCOPE_AGENT);
}
__device__ __forceinline__ ull packvt(float v, int tag) {
  return ((ull)(unsigned)tag << 32) | (ull)__float_as_uint(v);
}
// barrier that drains LDS (lgkm) but NOT vector-memory (vmcnt): publish
// stores stay in flight across it; tags make that safe.
__device__ __forceinline__ void lbar() {
  asm volatile("s_waitcnt lgkmcnt(0)\n\ts_barrier" ::: "memory");
}

#define FMA_8(ACC, W, VA, VB)                                   \
  ACC[0] = fmaf((W), (VA).x, ACC[0]); ACC[1] = fmaf((W), (VA).y, ACC[1]); \
  ACC[2] = fmaf((W), (VA).z, ACC[2]); ACC[3] = fmaf((W), (VA).w, ACC[3]); \
  ACC[4] = fmaf((W), (VB).x, ACC[4]); ACC[5] = fmaf((W), (VB).y, ACC[5]); \
  ACC[6] = fmaf((W), (VB).z, ACC[6]); ACC[7] = fmaf((W), (VB).w, ACC[7]);

// ---------------------------------------------------------------------------
// initK: K-major packed weight copies + zero the tag arrays (tags: 2*T*2048 ull).
// ---------------------------------------------------------------------------
__global__ void initK(const float* __restrict__ Wih_p0, const float* __restrict__ Whh_p0,
                      const float* __restrict__ Wih_p1, const float* __restrict__ Whh_p1,
                      const float* __restrict__ Wih_c0, const float* __restrict__ Whh_c0,
                      const float* __restrict__ Wih_c1, const float* __restrict__ Whh_c1,
                      const float* __restrict__ Wih_o,
                      float* wt_p0, float* wt_p1, float* wt_c0, float* wt_c1,
                      float* wt_o1, float* wt_o2, ull* tags) {
  const int NW = 458752 + 524288 + 131072 + 131072 + 131072 + 98304;
  const int gsz = gridDim.x * blockDim.x;
  for (int i = blockIdx.x * blockDim.x + threadIdx.x; i < NW; i += gsz) {
    int idx = i;
    if (idx < 458752) { int k = idx >> 10, c = idx & 1023;
      int wg = c >> 6, r6 = c & 63, gate = r6 >> 4, jl = r6 & 15;
      int col = gate * 256 + wg * 16 + jl;
      wt_p0[idx] = (k < 192) ? Wih_p0[col * 192 + k] : Whh_p0[col * 256 + (k - 192)]; continue; }
    idx -= 458752;
    if (idx < 524288) { int k = idx >> 10, c = idx & 1023;
      int wg = c >> 6, r6 = c & 63, gate = r6 >> 4, jl = r6 & 15;
      int col = gate * 256 + wg * 16 + jl;
      wt_p1[idx] = (k < 256) ? Wih_p1[col * 256 + k] : Whh_p1[col * 256 + (k - 256)]; continue; }
    idx -= 524288;
    if (idx < 131072) { int k = idx >> 9, r = idx & 511;
      wt_c0[idx] = (k < 128) ? Wih_c0[r * 128 + k] : Whh_c0[r * 128 + (k - 128)]; continue; }
    idx -= 131072;
    if (idx < 131072) { int k = idx >> 9, r = idx & 511;
      wt_c1[idx] = (k < 128) ? Wih_c1[r * 128 + k] : Whh_c1[r * 128 + (k - 128)]; continue; }
    idx -= 131072;
    if (idx < 131072) { int k = idx >> 9, r = idx & 511;
      wt_o1[idx] = Wih_o[r * 448 + k]; continue; }
    idx -= 131072;
    { int k = idx >> 9, r = idx & 511;
      wt_o2[idx] = Wih_o[r * 448 + 256 + k]; }
  }
  const size_t NT = (size_t)2 * T_ * 2048;
  for (size_t p = (size_t)blockIdx.x * blockDim.x + threadIdx.x; p < NT; p += gsz)
    tags[p] = 0ULL;
}

// ---------------------------------------------------------------------------
// opre2K: parallel over t. opre2[t][e][512] = Wih_o[:,256:448] @ x(t,e)  (bf16)
// ---------------------------------------------------------------------------
__global__ void opre2K(const float* __restrict__ feat, const float* __restrict__ wt_o2,
                       __hip_bfloat16* __restrict__ opre2) {
  __shared__ float xb[192 * 8];
  const int t = blockIdx.x, tid = threadIdx.x;
  const float* ft = feat + (size_t)t * 640;
  for (int idx = tid; idx < 192 * 8; idx += 256) {
    int k = idx >> 3, e = idx & 7;
    xb[idx] = (k < 128) ? ft[k] : ft[128 + e * 64 + (k - 128)];
  }
  __syncthreads();
  const int r = tid;
  float A0[8] = {0,0,0,0,0,0,0,0};
  float A1[8] = {0,0,0,0,0,0,0,0};
  const float4* x4 = (const float4*)xb;
  #pragma unroll 2
  for (int k = 0; k < 192; ++k) {
    float w0 = wt_o2[k * 512 + r];
    float w1 = wt_o2[k * 512 + 256 + r];
    float4 a = x4[k * 2], b = x4[k * 2 + 1];
    FMA_8(A0, w0, a, b);
    FMA_8(A1, w1, a, b);
  }
  #pragma unroll
  for (int e = 0; e < 8; ++e) {
    opre2[((size_t)t * 8 + e) * 512 + r]       = __float2bfloat16(A0[e]);
    opre2[((size_t)t * 8 + e) * 512 + 256 + r] = __float2bfloat16(A1[e]);
  }
}

// ---------------------------------------------------------------------------
// phaseA: 32 WGs. WG 0-15 = G1 (layer0), WG 16-31 = G2 (layer1, trailing).
// r7 LDS-weight compute structure + NEW tagged exchange:
//  - publish = one atomic b64 store (t+1)<<32|h2, NO drain, NO flags
//  - gather = prime loads (skip own slice), verify tags, retry stale only
//  - steady-state barriers are lgkm-only (publish stores fly across them)
//  - gather primes issue BEFORE the shadow compute so RTT overlaps FMAs
// ---------------------------------------------------------------------------
__launch_bounds__(256, 1)
__global__ void phaseA(const float* __restrict__ feat,
                       const float* __restrict__ pre_h0, const float* __restrict__ pre_c0,
                       const float* __restrict__ wt_p0, const float* __restrict__ wt_p1,
                       const float* __restrict__ b_p0, const float* __restrict__ b_p1,
                       ull* __restrict__ h0tag, ull* __restrict__ h1tag) {
  __shared__ float lds[38912];   // 155,648 B
  const int wg = blockIdx.x, tid = threadIdx.x;
  const int r6 = tid & 63, kq = tid >> 6;
  const int uj = tid >> 3, ue = tid & 7;

  if (wg < 16) {
    // ============================ G1: layer0 ============================
    float* wl   = lds;            // 28672: weights [k][64], k<448
    float* xbuf = lds + 28672;    // 1536: x(t) [k][e]
    float* hsf  = lds + 30208;    // 2048: h0(t-1) [k][e]
    float* gl   = lds + 32256;    // 2048: partials
    for (int idx = tid; idx < 28672; idx += 256)
      wl[idx] = wt_p0[(size_t)(idx >> 6) * 1024 + wg * 64 + (idx & 63)];
    const int j = wg * 16 + uj;
    float creg = 0.f, bi = 0.f, bff = 0.f, bg = 0.f, bo = 0.f;
    if (tid < 128) {
      creg = pre_c0[(ue * 2 + 0) * 256 + j];
      bi = b_p0[j]; bff = b_p0[256 + j]; bg = b_p0[512 + j]; bo = b_p0[768 + j];
    }
    for (int idx = tid; idx < 2048; idx += 256) {
      int k = idx >> 3, e = idx & 7;
      hsf[idx] = pre_h0[(e * 2 + 0) * 256 + k];
    }
    for (int idx = tid; idx < 1536; idx += 256) {
      int k = idx >> 3, e = idx & 7;
      xbuf[idx] = (k < 128) ? feat[k] : feat[128 + e * 64 + (k - 128)];
    }
    __syncthreads();
    float Ax[8] = {0,0,0,0,0,0,0,0};
    {
      const float4* x4 = (const float4*)xbuf;
      #pragma unroll 8
      for (int k = kq * 48; k < kq * 48 + 48; ++k) {
        float w = wl[k * 64 + r6];
        float4 a = x4[k * 2], b = x4[k * 2 + 1];
        FMA_8(Ax, w, a, b);
      }
    }
    for (int t = 0; t < T_; ++t) {
      float px[6];
      if (t + 1 < T_) {
        const float* ft1 = feat + (size_t)(t + 1) * 640;
        #pragma unroll
        for (int i = 0; i < 6; ++i) {
          int idx = tid + i * 256; int k = idx >> 3, e = idx & 7;
          px[i] = (k < 128) ? ft1[k] : ft1[128 + e * 64 + (k - 128)];
        }
      }
      float A[8];
      #pragma unroll
      for (int i = 0; i < 8; ++i) A[i] = Ax[i];
      {  // h-part: k in [192+kq*64, +64), weights from LDS
        const float4* h4 = (const float4*)hsf;
        const int kb = 192 + kq * 64;
        #pragma unroll 8
        for (int k = kb; k < kb + 64; ++k) {
          float w = wl[k * 64 + r6];
          int kk = k - 192;
          float4 a = h4[kk * 2], b = h4[kk * 2 + 1];
          FMA_8(A, w, a, b);
        }
      }
      {
        float4* g4 = (float4*)gl;
        g4[(kq * 64 + r6) * 2]     = make_float4(A[0], A[1], A[2], A[3]);
        g4[(kq * 64 + r6) * 2 + 1] = make_float4(A[4], A[5], A[6], A[7]);
      }
      lbar();                                      // B1: gl ready
      if (tid < 128) {
        float s0 = 0.f, s1 = 0.f, s2 = 0.f, s3 = 0.f;
        #pragma unroll
        for (int q = 0; q < 4; ++q) {
          s0 += gl[q * 512 + tid];       s1 += gl[q * 512 + 128 + tid];
          s2 += gl[q * 512 + 256 + tid]; s3 += gl[q * 512 + 384 + tid];
        }
        float c2 = sigm(s1 + bff) * creg + sigm(s0 + bi) * tanh_(s2 + bg);
        float h2 = sigm(s3 + bo) * tanh_(c2);
        creg = c2;
        __hip_atomic_store(&h0tag[(size_t)t * 2048 + wg * 128 + tid],
                           packvt(h2, t + 1), __ATOMIC_RELAXED, __HIP_MEMORY_SCOPE_AGENT);
        hsf[wg * 128 + tid] = h2;                  // own slice, fresh
      }
      if (t + 1 >= T_) break;
      // prime gather of h0(t) (other 15 slices) — in flight during refill+Ax
      ull v[8];
      const ull* gb = h0tag + (size_t)t * 2048;
      #pragma unroll
      for (int i = 0; i < 8; ++i) {
        int idx = tid + i * 256;
        v[i] = ((idx >> 7) != wg) ? aload64(gb + idx) : 0ULL;
      }
      #pragma unroll
      for (int i = 0; i < 6; ++i) xbuf[tid + i * 256] = px[i];
      lbar();                                      // B2: xbuf = x(t+1)
      #pragma unroll
      for (int i = 0; i < 8; ++i) Ax[i] = 0.f;
      {  // x-part of t+1 (gather RTT shadow)
        const float4* x4 = (const float4*)xbuf;
        #pragma unroll 8
        for (int k = kq * 48; k < kq * 48 + 48; ++k) {
          float w = wl[k * 64 + r6];
          float4 a = x4[k * 2], b = x4[k * 2 + 1];
          FMA_8(Ax, w, a, b);
        }
      }
      {  // verify + retry stale
        const int want = t + 1;
        bool all;
        do {
          all = true;
          #pragma unroll
          for (int i = 0; i < 8; ++i) {
            int idx = tid + i * 256;
            if ((idx >> 7) == wg) continue;
            if ((int)(v[i] >> 32) != want) {
              v[i] = aload64(gb + idx);
              if ((int)(v[i] >> 32) != want) all = false;
            }
          }
          if (!all) __builtin_amdgcn_s_sleep(1);
        } while (!all);
      }
      #pragma unroll
      for (int i = 0; i < 8; ++i) {
        int idx = tid + i * 256;
        if ((idx >> 7) != wg) hsf[idx] = __uint_as_float((unsigned)v[i]);
      }
      lbar();                                      // B3: hsf = h0(t)
    }
  } else {
    // ============================ G2: layer1 ============================
    const int wgl = wg - 16;
    float* wl  = lds;             // 32768: weights [k][64], k<512
    float* xh0 = lds + 32768;     // 2048: h0(t) [k][e]
    float* hsf = lds + 34816;     // 2048: h1(t-1) [k][e]
    float* gl  = lds + 36864;     // 2048
    for (int idx = tid; idx < 32768; idx += 256)
      wl[idx] = wt_p1[(size_t)(idx >> 6) * 1024 + wgl * 64 + (idx & 63)];
    const int j = wgl * 16 + uj;
    float creg = 0.f, bi = 0.f, bff = 0.f, bg = 0.f, bo = 0.f;
    if (tid < 128) {
      creg = pre_c0[(ue * 2 + 1) * 256 + j];
      bi = b_p1[j]; bff = b_p1[256 + j]; bg = b_p1[512 + j]; bo = b_p1[768 + j];
    }
    for (int idx = tid; idx < 2048; idx += 256) {
      int k = idx >> 3, e = idx & 7;
      hsf[idx] = pre_h0[(e * 2 + 1) * 256 + k];
    }
    __syncthreads();
    // Ax = h1-part for t=0 (from pre_h0 state)
    float Ax[8] = {0,0,0,0,0,0,0,0};
    {
      const float4* h4 = (const float4*)hsf;
      const int kb = 256 + kq * 64;
      #pragma unroll 8
      for (int k = kb; k < kb + 64; ++k) {
        float w = wl[k * 64 + r6];
        int kk = k - 256;
        float4 a = h4[kk * 2], b = h4[kk * 2 + 1];
        FMA_8(Ax, w, a, b);
      }
    }
    {  // gather h0(0): prime + verify (want = 1), all 2048
      ull v[8];
      #pragma unroll
      for (int i = 0; i < 8; ++i) v[i] = aload64(h0tag + tid + i * 256);
      bool all;
      do {
        all = true;
        #pragma unroll
        for (int i = 0; i < 8; ++i)
          if ((int)(v[i] >> 32) != 1) {
            v[i] = aload64(h0tag + tid + i * 256);
            if ((int)(v[i] >> 32) != 1) all = false;
          }
        if (!all) __builtin_amdgcn_s_sleep(1);
      } while (!all);
      #pragma unroll
      for (int i = 0; i < 8; ++i) xh0[tid + i * 256] = __uint_as_float((unsigned)v[i]);
    }
    __syncthreads();
    for (int t = 0; t < T_; ++t) {
      float A[8];
      #pragma unroll
      for (int i = 0; i < 8; ++i) A[i] = Ax[i];
      {  // h0-part: k in [kq*64, +64) from xh0
        const float4* x4 = (const float4*)xh0;
        #pragma unroll 8
        for (int k = kq * 64; k < kq * 64 + 64; ++k) {
          float w = wl[k * 64 + r6];
          float4 a = x4[k * 2], b = x4[k * 2 + 1];
          FMA_8(A, w, a, b);
        }
      }
      {
        float4* g4 = (float4*)gl;
        g4[(kq * 64 + r6) * 2]     = make_float4(A[0], A[1], A[2], A[3]);
        g4[(kq * 64 + r6) * 2 + 1] = make_float4(A[4], A[5], A[6], A[7]);
      }
      lbar();                                      // B1
      if (tid < 128) {
        float s0 = 0.f, s1 = 0.f, s2 = 0.f, s3 = 0.f;
        #pragma unroll
        for (int q = 0; q < 4; ++q) {
          s0 += gl[q * 512 + tid];       s1 += gl[q * 512 + 128 + tid];
          s2 += gl[q * 512 + 256 + tid]; s3 += gl[q * 512 + 384 + tid];
        }
        float c2 = sigm(s1 + bff) * creg + sigm(s0 + bi) * tanh_(s2 + bg);
        float h2 = sigm(s3 + bo) * tanh_(c2);
        creg = c2;
        __hip_atomic_store(&h1tag[(size_t)t * 2048 + wgl * 128 + tid],
                           packvt(h2, t + 1), __ATOMIC_RELAXED, __HIP_MEMORY_SCOPE_AGENT);
        hsf[wgl * 128 + tid] = h2;                 // own slice, fresh
      }
      if (t + 1 >= T_) break;
      // prime BOTH gathers now: h0(t+1) (long pole) + h1(t) (own group)
      ull v0[8], v1[8];
      const ull* g0 = h0tag + (size_t)(t + 1) * 2048;
      const ull* g1 = h1tag + (size_t)t * 2048;
      #pragma unroll
      for (int i = 0; i < 8; ++i) v0[i] = aload64(g0 + tid + i * 256);
      #pragma unroll
      for (int i = 0; i < 8; ++i) {
        int idx = tid + i * 256;
        v1[i] = ((idx >> 7) != wgl) ? aload64(g1 + idx) : 0ULL;
      }
      {  // verify h1(t) first (likely ready), write hsf
        const int want = t + 1;
        bool all;
        do {
          all = true;
          #pragma unroll
          for (int i = 0; i < 8; ++i) {
            int idx = tid + i * 256;
            if ((idx >> 7) == wgl) continue;
            if ((int)(v1[i] >> 32) != want) {
              v1[i] = aload64(g1 + idx);
              if ((int)(v1[i] >> 32) != want) all = false;
            }
          }
          if (!all) __builtin_amdgcn_s_sleep(1);
        } while (!all);
      }
      #pragma unroll
      for (int i = 0; i < 8; ++i) {
        int idx = tid + i * 256;
        if ((idx >> 7) != wgl) hsf[idx] = __uint_as_float((unsigned)v1[i]);
      }
      lbar();                                      // B2: hsf = h1(t)
      #pragma unroll
      for (int i = 0; i < 8; ++i) Ax[i] = 0.f;
      {  // h1-part of t+1 — h0(t+1) loads still in flight underneath
        const float4* h4 = (const float4*)hsf;
        const int kb = 256 + kq * 64;
        #pragma unroll 8
        for (int k = kb; k < kb + 64; ++k) {
          float w = wl[k * 64 + r6];
          int kk = k - 256;
          float4 a = h4[kk * 2], b = h4[kk * 2 + 1];
          FMA_8(Ax, w, a, b);
        }
      }
      {  // verify h0(t+1), write xh0
        const int want0 = t + 2;
        bool all;
        do {
          all = true;
          #pragma unroll
          for (int i = 0; i < 8; ++i) {
            if ((int)(v0[i] >> 32) != want0) {
              v0[i] = aload64(g0 + tid + i * 256);
              if ((int)(v0[i] >> 32) != want0) all = false;
            }
          }
          if (!all) __builtin_amdgcn_s_sleep(1);
        } while (!all);
      }
      #pragma unroll
      for (int i = 0; i < 8; ++i) xh0[tid + i * 256] = __uint_as_float((unsigned)v0[i]);
      lbar();                                      // B3: xh0 = h0(t+1)
    }
  }
}

// ---------------------------------------------------------------------------
// fcK: parallel over t. pre_out[t][e][c] = leaky(Wfc @ h1(t) + bfc)
// h1tag: [t][j*8+e] ull, fp32 value in low 32 bits.
// ---------------------------------------------------------------------------
__global__ void fcK(const ull* __restrict__ h1tag, const float* __restrict__ Wfc,
                    const float* __restrict__ bfc, float* __restrict__ pre_out) {
  __shared__ float hl[2048];
  const int t = blockIdx.x, tid = threadIdx.x;
  for (int idx = tid; idx < 2048; idx += 256)
    hl[idx] = __uint_as_float((unsigned)h1tag[(size_t)t * 2048 + idx]);
  __syncthreads();
  const int c = tid >> 1, half = tid & 1;
  float b = bfc[c];
  float acc[4] = {b, b, b, b};
  const float4* h4 = (const float4*)hl;
  const float* wrow = Wfc + c * 256;
  #pragma unroll 4
  for (int k = 0; k < 256; ++k) {
    float w = wrow[k];
    float4 x = h4[k * 2 + half];
    acc[0] = fmaf(w, x.x, acc[0]); acc[1] = fmaf(w, x.y, acc[1]);
    acc[2] = fmaf(w, x.z, acc[2]); acc[3] = fmaf(w, x.w, acc[3]);
  }
  #pragma unroll
  for (int i = 0; i < 4; ++i) {
    int e = half * 4 + i;
    float v = acc[i];
    v = (v > 0.f) ? v : 0.05f * v;
    pre_out[((size_t)t * 8 + e) * 128 + c] = v;
  }
}

// ---------------------------------------------------------------------------
// comm cell for phase B
// ---------------------------------------------------------------------------
__device__ __forceinline__ void comm_cell(
    const float* __restrict__ wt, const float* __restrict__ bias,
    const float* xin, float* hL, float* cL, float* glb, float* hout,
    float alpha, int tid) {
  const int r = tid;
  float A0[8] = {0,0,0,0,0,0,0,0};
  float A1[8] = {0,0,0,0,0,0,0,0};
  const float4* x4 = (const float4*)xin;
  #pragma unroll 2
  for (int k = 0; k < 128; ++k) {
    float w0 = wt[k * 512 + r];
    float w1 = wt[k * 512 + 256 + r];
    float4 a = x4[k * 2], b = x4[k * 2 + 1];
    FMA_8(A0, w0, a, b);
    FMA_8(A1, w1, a, b);
  }
  const float4* h4 = (const float4*)hL;
  #pragma unroll 2
  for (int k = 0; k < 128; ++k) {
    float w0 = wt[(128 + k) * 512 + r];
    float w1 = wt[(128 + k) * 512 + 256 + r];
    float4 a = h4[k * 2], b = h4[k * 2 + 1];
    FMA_8(A0, w0, a, b);
    FMA_8(A1, w1, a, b);
  }
  {
    float4* g4 = (float4*)glb;
    g4[r * 2]             = make_float4(A0[0], A0[1], A0[2], A0[3]);
    g4[r * 2 + 1]         = make_float4(A0[4], A0[5], A0[6], A0[7]);
    g4[(256 + r) * 2]     = make_float4(A1[0], A1[1], A1[2], A1[3]);
    g4[(256 + r) * 2 + 1] = make_float4(A1[4], A1[5], A1[6], A1[7]);
  }
  __syncthreads();
  for (int idx = tid; idx < 1024; idx += 256) {
    int jj = idx >> 3, tt = idx & 7;
    float gi = glb[jj * 8 + tt]         + bias[jj];
    float gf = glb[(128 + jj) * 8 + tt] + bias[128 + jj];
    float gg = glb[(256 + jj) * 8 + tt] + bias[256 + jj];
    float go = glb[(384 + jj) * 8 + tt] + bias[384 + jj];
    float cold = cL[idx], hold = hL[idx];
    float c2 = sigm(gf) * cold + sigm(gi) * tanh_(gg);
    float h2 = sigm(go) * tanh_(c2);
    float hb = fmaf(alpha, h2 - hold, hold);
    float cb = fmaf(alpha, c2 - cold, cold);
    hL[idx] = hb; cL[idx] = cb;
    if (hout) hout[idx] = hb;
  }
  __syncthreads();
}

// ---------------------------------------------------------------------------
// phaseB: parallel over t (8 timesteps / WG); emits opre1 (incl. b_o)
// ---------------------------------------------------------------------------
__launch_bounds__(256, 2)
__global__ void phaseB(const float* __restrict__ pre_out,
                       const float* __restrict__ wt_c0, const float* __restrict__ wt_c1,
                       const float* __restrict__ b_c0, const float* __restrict__ b_c1,
                       const float* __restrict__ wt_o1, const float* __restrict__ b_o,
                       float* __restrict__ opre1) {
  __shared__ float pol[128 * 8];
  __shared__ float ch0[128 * 8], cc0[128 * 8], ch1[128 * 8], cc1[128 * 8];
  __shared__ float h0b[128 * 8];
  __shared__ float glb[512 * 8];
  const int wg = blockIdx.x, tid = threadIdx.x;
  const int t0 = wg * 8;
  for (int idx = tid; idx < 1024; idx += 256) { ch0[idx]=0.f; cc0[idx]=0.f; ch1[idx]=0.f; cc1[idx]=0.f; }
  __syncthreads();
  float alpha = 1.0f;
  for (int rd = 0; rd < 3; ++rd) {
    for (int e = 0; e < E_; ++e) {
      for (int idx = tid; idx < 1024; idx += 256) {
        int tt = idx >> 7, k = idx & 127;
        pol[k * 8 + tt] = pre_out[(((size_t)(t0 + tt)) * 8 + e) * 128 + k];
      }
      __syncthreads();
      comm_cell(wt_c0, b_c0, pol, ch0, cc0, glb, h0b, alpha, tid);
      comm_cell(wt_c1, b_c1, h0b, ch1, cc1, glb, nullptr, alpha, tid);
    }
    alpha *= 0.333f;
  }
  {
    const int r = tid;
    float A0[8], A1[8];
    #pragma unroll
    for (int tt = 0; tt < 8; ++tt) { A0[tt] = b_o[r]; A1[tt] = b_o[256 + r]; }
    const float4* c04 = (const float4*)cc0;
    const float4* c14 = (const float4*)cc1;
    #pragma unroll 2
    for (int k = 0; k < 128; ++k) {
      float w0 = wt_o1[k * 512 + r], w1 = wt_o1[k * 512 + 256 + r];
      float4 a = c04[k * 2], b = c04[k * 2 + 1];
      FMA_8(A0, w0, a, b);
      FMA_8(A1, w1, a, b);
    }
    #pragma unroll 2
    for (int k = 0; k < 128; ++k) {
      float w0 = wt_o1[(128 + k) * 512 + r], w1 = wt_o1[(128 + k) * 512 + 256 + r];
      float4 a = c14[k * 2], b = c14[k * 2 + 1];
      FMA_8(A0, w0, a, b);
      FMA_8(A1, w1, a, b);
    }
    #pragma unroll
    for (int tt = 0; tt < 8; ++tt) {
      opre1[((size_t)(t0 + tt)) * 512 + r]       = A0[tt];
      opre1[((size_t)(t0 + tt)) * 512 + 256 + r] = A1[tt];
    }
  }
}

// ---------------------------------------------------------------------------
// phaseC: 8 WGs, one per ensemble e. No inter-WG sync; Whh_o in registers.
// ---------------------------------------------------------------------------
__launch_bounds__(256, 1)
__global__ void phaseC(const float* __restrict__ opre1, const __hip_bfloat16* __restrict__ opre2,
                       const float* __restrict__ Whh_o, const float* __restrict__ out_h0,
                       const float* __restrict__ out_c0, float* __restrict__ oh_g) {
  __shared__ float ohl[128];
  __shared__ float gl[512];
  const int e = blockIdx.x, tid = threadIdx.x;
  const int r0 = tid, r1 = tid + 256;
  float w0[128], w1[128];
  #pragma unroll
  for (int k = 0; k < 128; ++k) w0[k] = Whh_o[r0 * 128 + k];
  #pragma unroll
  for (int k = 0; k < 128; ++k) w1[k] = Whh_o[r1 * 128 + k];
  if (tid < 128) ohl[tid] = out_h0[e * 128 + tid];
  float creg = (tid < 128) ? out_c0[e * 128 + tid] : 0.f;
  __syncthreads();
  float p0a = opre1[r0], p0b = opre1[r1];
  float q0a = __bfloat162float(opre2[(size_t)e * 512 + r0]);
  float q0b = __bfloat162float(opre2[(size_t)e * 512 + r1]);
  for (int t = 0; t < T_; ++t) {
    float a0 = p0a + q0a, a1 = p0b + q0b;
    if (t + 1 < T_) {
      p0a = opre1[(size_t)(t + 1) * 512 + r0];
      p0b = opre1[(size_t)(t + 1) * 512 + r1];
      q0a = __bfloat162float(opre2[((size_t)(t + 1) * 8 + e) * 512 + r0]);
      q0b = __bfloat162float(opre2[((size_t)(t + 1) * 8 + e) * 512 + r1]);
    }
    const float4* o4 = (const float4*)ohl;
    #pragma unroll
    for (int kk = 0; kk < 32; ++kk) {
      float4 x = o4[kk];
      a0 = fmaf(w0[kk * 4 + 0], x.x, a0); a0 = fmaf(w0[kk * 4 + 1], x.y, a0);
      a0 = fmaf(w0[kk * 4 + 2], x.z, a0); a0 = fmaf(w0[kk * 4 + 3], x.w, a0);
      a1 = fmaf(w1[kk * 4 + 0], x.x, a1); a1 = fmaf(w1[kk * 4 + 1], x.y, a1);
      a1 = fmaf(w1[kk * 4 + 2], x.z, a1); a1 = fmaf(w1[kk * 4 + 3], x.w, a1);
    }
    gl[r0] = a0; gl[r1] = a1;
    __syncthreads();
    if (tid < 128) {
      float gi = gl[tid], gf = gl[128 + tid], gg = gl[256 + tid], go = gl[384 + tid];
      float c2 = sigm(gf) * creg + sigm(gi) * tanh_(gg);
      float h2 = sigm(go) * tanh_(c2);
      creg = c2;
      ohl[tid] = h2;
      oh_g[(size_t)t * 1024 + e * 128 + tid] = h2;
    }
    __syncthreads();
  }
}

// ---------------------------------------------------------------------------
// phaseD: parallel over t: softmaxes
// ---------------------------------------------------------------------------
__global__ void phaseD(const float* __restrict__ oh_g,
                       const float* __restrict__ Wtar, const float* __restrict__ btar,
                       const float* __restrict__ Wdir, const float* __restrict__ bdir,
                       float* __restrict__ outp) {
  __shared__ float ohl[1024];
  const int t = blockIdx.x, tid = threadIdx.x;  // 64 threads
  for (int idx = tid; idx < 1024; idx += 64) ohl[idx] = oh_g[(size_t)t * 1024 + idx];
  __syncthreads();
  const int f = tid;
  for (int e = 0; e < E_; ++e) {
    float acc = btar[f];
    const float* wr = Wtar + f * 128;
    #pragma unroll 4
    for (int k = 0; k < 128; ++k) acc = fmaf(wr[k], ohl[e * 128 + k], acc);
    float m = acc;
    #pragma unroll
    for (int off = 32; off; off >>= 1) m = fmaxf(m, __shfl_xor(m, off, 64));
    float ex = __expf(acc - m);
    float s = ex;
    #pragma unroll
    for (int off = 32; off; off >>= 1) s += __shfl_xor(s, off, 64);
    outp[((size_t)t * 8 + e) * 64 + f] = ex / s;
  }
  if (tid < 8) {
    int e = tid;
    float d0 = bdir[0], d1 = bdir[1], d2 = bdir[2];
    #pragma unroll 4
    for (int k = 0; k < 128; ++k) {
      float x = ohl[e * 128 + k];
      d0 = fmaf(Wdir[k], x, d0);
      d1 = fmaf(Wdir[128 + k], x, d1);
      d2 = fmaf(Wdir[256 + k], x, d2);
    }
    float m = fmaxf(d0, fmaxf(d1, d2));
    float x0 = __expf(d0 - m), x1 = __expf(d1 - m), x2 = __expf(d2 - m);
    float s = x0 + x1 + x2;
    float* dp = outp + (size_t)T_ * 8 * 64 + ((size_t)t * 8 + e) * 3;
    dp[0] = x0 / s; dp[1] = x1 / s; dp[2] = x2 / s;
  }
}

extern "C" void kernel_launch(void* const* d_in, const int* in_sizes, int n_in,
                              void* d_out, int out_size, void* d_ws, size_t ws_size,
                              hipStream_t stream) {
  (void)in_sizes; (void)n_in; (void)out_size; (void)ws_size;
  const float* feat   = (const float*)d_in[0];
  const float* pre_h0 = (const float*)d_in[1];
  const float* pre_c0 = (const float*)d_in[2];
  const float* out_h0 = (const float*)d_in[3];
  const float* out_c0 = (const float*)d_in[4];
  const float* Wih_p0 = (const float*)d_in[5];
  const float* Whh_p0 = (const float*)d_in[6];
  const float* b_p0   = (const float*)d_in[7];
  const float* Wih_p1 = (const float*)d_in[8];
  const float* Whh_p1 = (const float*)d_in[9];
  const float* b_p1   = (const float*)d_in[10];
  const float* Wfc    = (const float*)d_in[11];
  const float* bfc    = (const float*)d_in[12];
  const float* Wih_c0 = (const float*)d_in[13];
  const float* Whh_c0 = (const float*)d_in[14];
  const float* b_c0   = (const float*)d_in[15];
  const float* Wih_c1 = (const float*)d_in[16];
  const float* Whh_c1 = (const float*)d_in[17];
  const float* b_c1   = (const float*)d_in[18];
  const float* Wih_o  = (const float*)d_in[19];
  const float* Whh_o  = (const float*)d_in[20];
  const float* b_o    = (const float*)d_in[21];
  const float* Wtar   = (const float*)d_in[22];
  const float* btar   = (const float*)d_in[23];
  const float* Wdir   = (const float*)d_in[24];
  const float* bdir   = (const float*)d_in[25];
  float* outp = (float*)d_out;

  float* ws = (float*)d_ws;
  size_t off = 0;
  float* pre_outB = ws + off; off += (size_t)T_ * E_ * 128;
  float* opre1    = ws + off; off += (size_t)T_ * 512;
  float* oh_g     = ws + off; off += (size_t)T_ * E_ * 128;
  float* wt_p0    = ws + off; off += (size_t)448 * 1024;
  float* wt_p1    = ws + off; off += (size_t)512 * 1024;
  float* wt_c0    = ws + off; off += (size_t)256 * 512;
  float* wt_c1    = ws + off; off += (size_t)256 * 512;
  float* wt_o1    = ws + off; off += (size_t)256 * 512;
  float* wt_o2    = ws + off; off += (size_t)192 * 512;
  __hip_bfloat16* opre2 = (__hip_bfloat16*)(ws + off);
  off += (size_t)T_ * E_ * 512 / 2;
  ull* h0tag = (ull*)(ws + off); off += (size_t)T_ * 2048 * 2;   // 64 MB
  ull* h1tag = (ull*)(ws + off); off += (size_t)T_ * 2048 * 2;   // 64 MB (contiguous after h0tag)

  initK<<<dim3(1024), dim3(256), 0, stream>>>(
      Wih_p0, Whh_p0, Wih_p1, Whh_p1, Wih_c0, Whh_c0, Wih_c1, Whh_c1, Wih_o,
      wt_p0, wt_p1, wt_c0, wt_c1, wt_o1, wt_o2, h0tag);
  opre2K<<<dim3(T_), dim3(256), 0, stream>>>(feat, wt_o2, opre2);
  phaseA<<<dim3(32), dim3(256), 0, stream>>>(
      feat, pre_h0, pre_c0, wt_p0, wt_p1, b_p0, b_p1, h0tag, h1tag);
  fcK<<<dim3(T_), dim3(256), 0, stream>>>(h1tag, Wfc, bfc, pre_outB);
  phaseB<<<dim3(T_ / 8), dim3(256), 0, stream>>>(
      pre_outB, wt_c0, wt_c1, b_c0, b_c1, wt_o1, b_o, opre1);
  phaseC<<<dim3(E_), dim3(256), 0, stream>>>(
      opre1, opre2, Whh_o, out_h0, out_c0, oh_g);
  phaseD<<<dim3(T_), dim3(64), 0, stream>>>(oh_g, Wtar, btar, Wdir, bdir, outp);
}

// Round 9
// 33659.677 us; speedup vs baseline: 1.1695x; 1.1695x over previous
//
#include <hip/hip_runtime.h>
#include <hip/hip_bf16.h>

// Sizes from the reference
#define T_   4096
#define E_   8

typedef unsigned long long ull;

__device__ __forceinline__ float sigm(float x)  { return 1.0f / (1.0f + __expf(-x)); }
__device__ __forceinline__ float tanh_(float x) { return 1.0f - 2.0f / (__expf(2.0f * x) + 1.0f); }

__device__ __forceinline__ ull aload64(const ull* p) {
  return __hip_atomic_load(p, __ATOMIC_RELAXED, __HIP_MEMORY_SCOPE_AGENT);
}
__device__ __forceinline__ int aload32(const int* p) {
  return __hip_atomic_load(p, __ATOMIC_RELAXED, __HIP_MEMORY_SCOPE_AGENT);
}
// barrier draining LDS (lgkm) but not vector memory
__device__ __forceinline__ void lbar() {
  asm volatile("s_waitcnt lgkmcnt(0)\n\ts_barrier" ::: "memory");
}

#define FMA_8(ACC, W, VA, VB)                                   \
  ACC[0] = fmaf((W), (VA).x, ACC[0]); ACC[1] = fmaf((W), (VA).y, ACC[1]); \
  ACC[2] = fmaf((W), (VA).z, ACC[2]); ACC[3] = fmaf((W), (VA).w, ACC[3]); \
  ACC[4] = fmaf((W), (VB).x, ACC[4]); ACC[5] = fmaf((W), (VB).y, ACC[5]); \
  ACC[6] = fmaf((W), (VB).z, ACC[6]); ACC[7] = fmaf((W), (VB).w, ACC[7]);

// ---------------------------------------------------------------------------
// initK: K-major packed weight copies + zero the (small) flag rings.
// ---------------------------------------------------------------------------
__global__ void initK(const float* __restrict__ Wih_p0, const float* __restrict__ Whh_p0,
                      const float* __restrict__ Wih_p1, const float* __restrict__ Whh_p1,
                      const float* __restrict__ Wih_c0, const float* __restrict__ Whh_c0,
                      const float* __restrict__ Wih_c1, const float* __restrict__ Whh_c1,
                      const float* __restrict__ Wih_o,
                      float* wt_p0, float* wt_p1, float* wt_c0, float* wt_c1,
                      float* wt_o1, float* wt_o2, int* flags) {
  const int NW = 458752 + 524288 + 131072 + 131072 + 131072 + 98304;
  const int NF = 2 * 64 * 16 * 32;              // two 64-slot flag rings
  const int NTOT = NW + NF;
  const int gsz = gridDim.x * blockDim.x;
  for (int i = blockIdx.x * blockDim.x + threadIdx.x; i < NTOT; i += gsz) {
    int idx = i;
    if (idx < 458752) { int k = idx >> 10, c = idx & 1023;
      int wg = c >> 6, r6 = c & 63, gate = r6 >> 4, jl = r6 & 15;
      int col = gate * 256 + wg * 16 + jl;
      wt_p0[idx] = (k < 192) ? Wih_p0[col * 192 + k] : Whh_p0[col * 256 + (k - 192)]; continue; }
    idx -= 458752;
    if (idx < 524288) { int k = idx >> 10, c = idx & 1023;
      int wg = c >> 6, r6 = c & 63, gate = r6 >> 4, jl = r6 & 15;
      int col = gate * 256 + wg * 16 + jl;
      wt_p1[idx] = (k < 256) ? Wih_p1[col * 256 + k] : Whh_p1[col * 256 + (k - 256)]; continue; }
    idx -= 524288;
    if (idx < 131072) { int k = idx >> 9, r = idx & 511;
      wt_c0[idx] = (k < 128) ? Wih_c0[r * 128 + k] : Whh_c0[r * 128 + (k - 128)]; continue; }
    idx -= 131072;
    if (idx < 131072) { int k = idx >> 9, r = idx & 511;
      wt_c1[idx] = (k < 128) ? Wih_c1[r * 128 + k] : Whh_c1[r * 128 + (k - 128)]; continue; }
    idx -= 131072;
    if (idx < 131072) { int k = idx >> 9, r = idx & 511;
      wt_o1[idx] = Wih_o[r * 448 + k]; continue; }
    idx -= 131072;
    if (idx < 98304) { int k = idx >> 9, r = idx & 511;
      wt_o2[idx] = Wih_o[r * 448 + 256 + k]; continue; }
    idx -= 98304;
    flags[idx] = 0;
  }
}

// ---------------------------------------------------------------------------
// opre2K: parallel over t. opre2[t][e][512] = Wih_o[:,256:448] @ x(t,e)  (bf16)
// ---------------------------------------------------------------------------
__global__ void opre2K(const float* __restrict__ feat, const float* __restrict__ wt_o2,
                       __hip_bfloat16* __restrict__ opre2) {
  __shared__ float xb[192 * 8];
  const int t = blockIdx.x, tid = threadIdx.x;
  const float* ft = feat + (size_t)t * 640;
  for (int idx = tid; idx < 192 * 8; idx += 256) {
    int k = idx >> 3, e = idx & 7;
    xb[idx] = (k < 128) ? ft[k] : ft[128 + e * 64 + (k - 128)];
  }
  __syncthreads();
  const int r = tid;
  float A0[8] = {0,0,0,0,0,0,0,0};
  float A1[8] = {0,0,0,0,0,0,0,0};
  const float4* x4 = (const float4*)xb;
  #pragma unroll 2
  for (int k = 0; k < 192; ++k) {
    float w0 = wt_o2[k * 512 + r];
    float w1 = wt_o2[k * 512 + 256 + r];
    float4 a = x4[k * 2], b = x4[k * 2 + 1];
    FMA_8(A0, w0, a, b);
    FMA_8(A1, w1, a, b);
  }
  #pragma unroll
  for (int e = 0; e < 8; ++e) {
    opre2[((size_t)t * 8 + e) * 512 + r]       = __float2bfloat16(A0[e]);
    opre2[((size_t)t * 8 + e) * 512 + 256 + r] = __float2bfloat16(A1[e]);
  }
}

// ---------------------------------------------------------------------------
// phaseA: 32 WGs. WG 0-15 = G1 (layer0), WG 16-31 = G2 (layer1, trailing).
// r7 structure (LDS weights, flag sync) + RING exchange: h0ring/h1ring are
// 8-slot (64 KB) hot buffers; flags are 64-slot value-tagged rings (poll for
// == t+1; stale = t+1-64, no reset). Entire sync working set ~160 KB stays
// hot at the coherence point -> no cold-HBM lines in the step loop.
// h1 additionally streamed to h1all via plain stores (for fcK, read later).
// Back-pressure: G1 at step t polls flagsB[t-8]==t-7 before overwriting
// h0ring slot t&7 (normally pre-satisfied; G2 trails by ~1-2 steps).
// ---------------------------------------------------------------------------
__launch_bounds__(256, 1)
__global__ void phaseA(const float* __restrict__ feat,
                       const float* __restrict__ pre_h0, const float* __restrict__ pre_c0,
                       const float* __restrict__ wt_p0, const float* __restrict__ wt_p1,
                       const float* __restrict__ b_p0, const float* __restrict__ b_p1,
                       float* __restrict__ h0ring, float* __restrict__ h1ring,
                       float* __restrict__ h1all,
                       int* __restrict__ flagsA, int* __restrict__ flagsB) {
  __shared__ float lds[38912];   // 155,648 B
  const int wg = blockIdx.x, tid = threadIdx.x;
  const int r6 = tid & 63, kq = tid >> 6;
  const int uj = tid >> 3, ue = tid & 7;

  if (wg < 16) {
    // ============================ G1: layer0 ============================
    float* wl   = lds;            // 28672: weights [k][64], k<448
    float* xbuf = lds + 28672;    // 1536: x(t) [k][e]
    float* hsf  = lds + 30208;    // 2048: h0(t-1) [k][e]
    float* gl   = lds + 32256;    // 2048: partials
    for (int idx = tid; idx < 28672; idx += 256)
      wl[idx] = wt_p0[(size_t)(idx >> 6) * 1024 + wg * 64 + (idx & 63)];
    const int j = wg * 16 + uj;
    float creg = 0.f, bi = 0.f, bff = 0.f, bg = 0.f, bo = 0.f;
    if (tid < 128) {
      creg = pre_c0[(ue * 2 + 0) * 256 + j];
      bi = b_p0[j]; bff = b_p0[256 + j]; bg = b_p0[512 + j]; bo = b_p0[768 + j];
    }
    for (int idx = tid; idx < 2048; idx += 256) {
      int k = idx >> 3, e = idx & 7;
      hsf[idx] = pre_h0[(e * 2 + 0) * 256 + k];
    }
    for (int idx = tid; idx < 1536; idx += 256) {
      int k = idx >> 3, e = idx & 7;
      xbuf[idx] = (k < 128) ? feat[k] : feat[128 + e * 64 + (k - 128)];
    }
    __syncthreads();
    float Ax[8] = {0,0,0,0,0,0,0,0};
    {
      const float4* x4 = (const float4*)xbuf;
      #pragma unroll 8
      for (int k = kq * 48; k < kq * 48 + 48; ++k) {
        float w = wl[k * 64 + r6];
        float4 a = x4[k * 2], b = x4[k * 2 + 1];
        FMA_8(Ax, w, a, b);
      }
    }
    for (int t = 0; t < T_; ++t) {
      float px[6];
      if (t + 1 < T_) {
        const float* ft1 = feat + (size_t)(t + 1) * 640;
        #pragma unroll
        for (int i = 0; i < 6; ++i) {
          int idx = tid + i * 256; int k = idx >> 3, e = idx & 7;
          px[i] = (k < 128) ? ft1[k] : ft1[128 + e * 64 + (k - 128)];
        }
      }
      float A[8];
      #pragma unroll
      for (int i = 0; i < 8; ++i) A[i] = Ax[i];
      {  // h-part: k in [192+kq*64, +64), weights from LDS
        const float4* h4 = (const float4*)hsf;
        const int kb = 192 + kq * 64;
        #pragma unroll 8
        for (int k = kb; k < kb + 64; ++k) {
          float w = wl[k * 64 + r6];
          int kk = k - 192;
          float4 a = h4[kk * 2], b = h4[kk * 2 + 1];
          FMA_8(A, w, a, b);
        }
      }
      {
        float4* g4 = (float4*)gl;
        g4[(kq * 64 + r6) * 2]     = make_float4(A[0], A[1], A[2], A[3]);
        g4[(kq * 64 + r6) * 2 + 1] = make_float4(A[4], A[5], A[6], A[7]);
      }
      if (tid >= 240 && t >= 8) {                  // ring back-pressure (pre-satisfied)
        const int* fp = flagsB + ((size_t)((t - 8) & 63) * 16 + (tid - 240)) * 32;
        while (aload32(fp) != t - 7) __builtin_amdgcn_s_sleep(1);
      }
      lbar();                                      // S1: gl ready, backpressure ok
      if (tid < 128) {
        float s0 = 0.f, s1 = 0.f, s2 = 0.f, s3 = 0.f;
        #pragma unroll
        for (int q = 0; q < 4; ++q) {
          s0 += gl[q * 512 + tid];       s1 += gl[q * 512 + 128 + tid];
          s2 += gl[q * 512 + 256 + tid]; s3 += gl[q * 512 + 384 + tid];
        }
        float c2 = sigm(s1 + bff) * creg + sigm(s0 + bi) * tanh_(s2 + bg);
        float h2 = sigm(s3 + bo) * tanh_(c2);
        creg = c2;
        __hip_atomic_store(&h0ring[(size_t)(t & 7) * 2048 + wg * 128 + tid], h2,
                           __ATOMIC_RELAXED, __HIP_MEMORY_SCOPE_AGENT);
      }
      __syncthreads();                             // S2: publish drained (vmcnt0)
      if (tid == 0)
        __hip_atomic_store(&flagsA[((size_t)(t & 63) * 16 + wg) * 32], t + 1,
                           __ATOMIC_RELAXED, __HIP_MEMORY_SCOPE_AGENT);
      if (t + 1 >= T_) break;
      #pragma unroll
      for (int i = 0; i < 6; ++i) xbuf[tid + i * 256] = px[i];
      lbar();                                      // S3: xbuf = x(t+1)
      #pragma unroll
      for (int i = 0; i < 8; ++i) Ax[i] = 0.f;
      {  // x-part of t+1 in the sync shadow
        const float4* x4 = (const float4*)xbuf;
        #pragma unroll 8
        for (int k = kq * 48; k < kq * 48 + 48; ++k) {
          float w = wl[k * 64 + r6];
          float4 a = x4[k * 2], b = x4[k * 2 + 1];
          FMA_8(Ax, w, a, b);
        }
      }
      if (tid < 16) {                              // parallel 16-line detect
        const int* fp = flagsA + ((size_t)(t & 63) * 16 + tid) * 32;
        while (aload32(fp) != t + 1) __builtin_amdgcn_s_sleep(1);
      }
      lbar();                                      // S4: all 16 published
      {
        const ull* s8 = (const ull*)(h0ring + (size_t)(t & 7) * 2048);
        ull* d8 = (ull*)hsf;
        #pragma unroll
        for (int i = 0; i < 4; ++i) d8[tid * 4 + i] = aload64(s8 + tid * 4 + i);
      }
      lbar();                                      // S5: hsf = h0(t)
    }
  } else {
    // ============================ G2: layer1 ============================
    const int wgl = wg - 16;
    float* wl  = lds;             // 32768: weights [k][64], k<512
    float* xh0 = lds + 32768;     // 2048: h0(t) [k][e]
    float* hsf = lds + 34816;     // 2048: h1(t-1) [k][e]
    float* gl  = lds + 36864;     // 2048
    for (int idx = tid; idx < 32768; idx += 256)
      wl[idx] = wt_p1[(size_t)(idx >> 6) * 1024 + wgl * 64 + (idx & 63)];
    const int j = wgl * 16 + uj;
    float creg = 0.f, bi = 0.f, bff = 0.f, bg = 0.f, bo = 0.f;
    if (tid < 128) {
      creg = pre_c0[(ue * 2 + 1) * 256 + j];
      bi = b_p1[j]; bff = b_p1[256 + j]; bg = b_p1[512 + j]; bo = b_p1[768 + j];
    }
    for (int idx = tid; idx < 2048; idx += 256) {
      int k = idx >> 3, e = idx & 7;
      hsf[idx] = pre_h0[(e * 2 + 1) * 256 + k];
    }
    __syncthreads();
    if (tid < 16) {                                // step-0 flags
      const int* fp = flagsA + (size_t)tid * 32;
      while (aload32(fp) != 1) __builtin_amdgcn_s_sleep(1);
    }
    __syncthreads();
    {
      const ull* s8 = (const ull*)h0ring;          // slot 0
      ull* d8 = (ull*)xh0;
      #pragma unroll
      for (int i = 0; i < 4; ++i) d8[tid * 4 + i] = aload64(s8 + tid * 4 + i);
    }
    __syncthreads();
    float Ax[8] = {0,0,0,0,0,0,0,0};
    {
      const float4* x4 = (const float4*)xh0;
      #pragma unroll 8
      for (int k = kq * 64; k < kq * 64 + 64; ++k) {
        float w = wl[k * 64 + r6];
        float4 a = x4[k * 2], b = x4[k * 2 + 1];
        FMA_8(Ax, w, a, b);
      }
    }
    for (int t = 0; t < T_; ++t) {
      float A[8];
      #pragma unroll
      for (int i = 0; i < 8; ++i) A[i] = Ax[i];
      {  // h1-part: k in [256+kq*64, +64), weights from LDS
        const float4* h4 = (const float4*)hsf;
        const int kb = 256 + kq * 64;
        #pragma unroll 8
        for (int k = kb; k < kb + 64; ++k) {
          float w = wl[k * 64 + r6];
          int kk = k - 256;
          float4 a = h4[kk * 2], b = h4[kk * 2 + 1];
          FMA_8(A, w, a, b);
        }
      }
      {
        float4* g4 = (float4*)gl;
        g4[(kq * 64 + r6) * 2]     = make_float4(A[0], A[1], A[2], A[3]);
        g4[(kq * 64 + r6) * 2 + 1] = make_float4(A[4], A[5], A[6], A[7]);
      }
      lbar();                                      // S1
      if (tid < 128) {
        float s0 = 0.f, s1 = 0.f, s2 = 0.f, s3 = 0.f;
        #pragma unroll
        for (int q = 0; q < 4; ++q) {
          s0 += gl[q * 512 + tid];       s1 += gl[q * 512 + 128 + tid];
          s2 += gl[q * 512 + 256 + tid]; s3 += gl[q * 512 + 384 + tid];
        }
        float c2 = sigm(s1 + bff) * creg + sigm(s0 + bi) * tanh_(s2 + bg);
        float h2 = sigm(s3 + bo) * tanh_(c2);
        creg = c2;
        __hip_atomic_store(&h1ring[(size_t)(t & 7) * 2048 + wgl * 128 + tid], h2,
                           __ATOMIC_RELAXED, __HIP_MEMORY_SCOPE_AGENT);
        h1all[(size_t)t * 2048 + wgl * 128 + tid] = h2;   // plain stream for fcK
      }
      __syncthreads();                             // S2: publish drained
      if (tid == 0)
        __hip_atomic_store(&flagsB[((size_t)(t & 63) * 16 + wgl) * 32], t + 1,
                           __ATOMIC_RELAXED, __HIP_MEMORY_SCOPE_AGENT);
      if (t + 1 >= T_) break;
      if (tid < 32) {                              // combined detect
        const int* fp = (tid < 16)
            ? flagsA + ((size_t)((t + 1) & 63) * 16 + tid) * 32
            : flagsB + ((size_t)(t & 63) * 16 + (tid - 16)) * 32;
        const int want = (tid < 16) ? t + 2 : t + 1;
        while (aload32(fp) != want) __builtin_amdgcn_s_sleep(1);
      }
      lbar();                                      // S3: both ready
      {                                            // both gathers back-to-back
        const ull* s0p = (const ull*)(h0ring + (size_t)((t + 1) & 7) * 2048);
        const ull* s1p = (const ull*)(h1ring + (size_t)(t & 7) * 2048);
        ull v0[4], v1[4];
        #pragma unroll
        for (int i = 0; i < 4; ++i) v0[i] = aload64(s0p + tid * 4 + i);
        #pragma unroll
        for (int i = 0; i < 4; ++i) v1[i] = aload64(s1p + tid * 4 + i);
        ull* d0 = (ull*)xh0; ull* d1 = (ull*)hsf;
        #pragma unroll
        for (int i = 0; i < 4; ++i) { d0[tid * 4 + i] = v0[i]; d1[tid * 4 + i] = v1[i]; }
      }
      lbar();                                      // S4: xh0=h0(t+1), hsf=h1(t)
      #pragma unroll
      for (int i = 0; i < 8; ++i) Ax[i] = 0.f;
      {  // h0-part of t+1
        const float4* x4 = (const float4*)xh0;
        #pragma unroll 8
        for (int k = kq * 64; k < kq * 64 + 64; ++k) {
          float w = wl[k * 64 + r6];
          float4 a = x4[k * 2], b = x4[k * 2 + 1];
          FMA_8(Ax, w, a, b);
        }
      }
    }
  }
}

// ---------------------------------------------------------------------------
// fcK: parallel over t. pre_out[t][e][c] = leaky(Wfc @ h1all[t] + bfc)
// ---------------------------------------------------------------------------
__global__ void fcK(const float* __restrict__ h1all, const float* __restrict__ Wfc,
                    const float* __restrict__ bfc, float* __restrict__ pre_out) {
  __shared__ float hl[2048];
  const int t = blockIdx.x, tid = threadIdx.x;
  for (int idx = tid; idx < 2048; idx += 256) hl[idx] = h1all[(size_t)t * 2048 + idx];
  __syncthreads();
  const int c = tid >> 1, half = tid & 1;
  float b = bfc[c];
  float acc[4] = {b, b, b, b};
  const float4* h4 = (const float4*)hl;
  const float* wrow = Wfc + c * 256;
  #pragma unroll 4
  for (int k = 0; k < 256; ++k) {
    float w = wrow[k];
    float4 x = h4[k * 2 + half];
    acc[0] = fmaf(w, x.x, acc[0]); acc[1] = fmaf(w, x.y, acc[1]);
    acc[2] = fmaf(w, x.z, acc[2]); acc[3] = fmaf(w, x.w, acc[3]);
  }
  #pragma unroll
  for (int i = 0; i < 4; ++i) {
    int e = half * 4 + i;
    float v = acc[i];
    v = (v > 0.f) ? v : 0.05f * v;
    pre_out[((size_t)t * 8 + e) * 128 + c] = v;
  }
}

// ---------------------------------------------------------------------------
// comm cell for phase B
// ---------------------------------------------------------------------------
__device__ __forceinline__ void comm_cell(
    const float* __restrict__ wt, const float* __restrict__ bias,
    const float* xin, float* hL, float* cL, float* glb, float* hout,
    float alpha, int tid) {
  const int r = tid;
  float A0[8] = {0,0,0,0,0,0,0,0};
  float A1[8] = {0,0,0,0,0,0,0,0};
  const float4* x4 = (const float4*)xin;
  #pragma unroll 2
  for (int k = 0; k < 128; ++k) {
    float w0 = wt[k * 512 + r];
    float w1 = wt[k * 512 + 256 + r];
    float4 a = x4[k * 2], b = x4[k * 2 + 1];
    FMA_8(A0, w0, a, b);
    FMA_8(A1, w1, a, b);
  }
  const float4* h4 = (const float4*)hL;
  #pragma unroll 2
  for (int k = 0; k < 128; ++k) {
    float w0 = wt[(128 + k) * 512 + r];
    float w1 = wt[(128 + k) * 512 + 256 + r];
    float4 a = h4[k * 2], b = h4[k * 2 + 1];
    FMA_8(A0, w0, a, b);
    FMA_8(A1, w1, a, b);
  }
  {
    float4* g4 = (float4*)glb;
    g4[r * 2]             = make_float4(A0[0], A0[1], A0[2], A0[3]);
    g4[r * 2 + 1]         = make_float4(A0[4], A0[5], A0[6], A0[7]);
    g4[(256 + r) * 2]     = make_float4(A1[0], A1[1], A1[2], A1[3]);
    g4[(256 + r) * 2 + 1] = make_float4(A1[4], A1[5], A1[6], A1[7]);
  }
  __syncthreads();
  for (int idx = tid; idx < 1024; idx += 256) {
    int jj = idx >> 3, tt = idx & 7;
    float gi = glb[jj * 8 + tt]         + bias[jj];
    float gf = glb[(128 + jj) * 8 + tt] + bias[128 + jj];
    float gg = glb[(256 + jj) * 8 + tt] + bias[256 + jj];
    float go = glb[(384 + jj) * 8 + tt] + bias[384 + jj];
    float cold = cL[idx], hold = hL[idx];
    float c2 = sigm(gf) * cold + sigm(gi) * tanh_(gg);
    float h2 = sigm(go) * tanh_(c2);
    float hb = fmaf(alpha, h2 - hold, hold);
    float cb = fmaf(alpha, c2 - cold, cold);
    hL[idx] = hb; cL[idx] = cb;
    if (hout) hout[idx] = hb;
  }
  __syncthreads();
}

// ---------------------------------------------------------------------------
// phaseB: parallel over t (8 timesteps / WG); emits opre1 (incl. b_o)
// ---------------------------------------------------------------------------
__launch_bounds__(256, 2)
__global__ void phaseB(const float* __restrict__ pre_out,
                       const float* __restrict__ wt_c0, const float* __restrict__ wt_c1,
                       const float* __restrict__ b_c0, const float* __restrict__ b_c1,
                       const float* __restrict__ wt_o1, const float* __restrict__ b_o,
                       float* __restrict__ opre1) {
  __shared__ float pol[128 * 8];
  __shared__ float ch0[128 * 8], cc0[128 * 8], ch1[128 * 8], cc1[128 * 8];
  __shared__ float h0b[128 * 8];
  __shared__ float glb[512 * 8];
  const int wg = blockIdx.x, tid = threadIdx.x;
  const int t0 = wg * 8;
  for (int idx = tid; idx < 1024; idx += 256) { ch0[idx]=0.f; cc0[idx]=0.f; ch1[idx]=0.f; cc1[idx]=0.f; }
  __syncthreads();
  float alpha = 1.0f;
  for (int rd = 0; rd < 3; ++rd) {
    for (int e = 0; e < E_; ++e) {
      for (int idx = tid; idx < 1024; idx += 256) {
        int tt = idx >> 7, k = idx & 127;
        pol[k * 8 + tt] = pre_out[(((size_t)(t0 + tt)) * 8 + e) * 128 + k];
      }
      __syncthreads();
      comm_cell(wt_c0, b_c0, pol, ch0, cc0, glb, h0b, alpha, tid);
      comm_cell(wt_c1, b_c1, h0b, ch1, cc1, glb, nullptr, alpha, tid);
    }
    alpha *= 0.333f;
  }
  {
    const int r = tid;
    float A0[8], A1[8];
    #pragma unroll
    for (int tt = 0; tt < 8; ++tt) { A0[tt] = b_o[r]; A1[tt] = b_o[256 + r]; }
    const float4* c04 = (const float4*)cc0;
    const float4* c14 = (const float4*)cc1;
    #pragma unroll 2
    for (int k = 0; k < 128; ++k) {
      float w0 = wt_o1[k * 512 + r], w1 = wt_o1[k * 512 + 256 + r];
      float4 a = c04[k * 2], b = c04[k * 2 + 1];
      FMA_8(A0, w0, a, b);
      FMA_8(A1, w1, a, b);
    }
    #pragma unroll 2
    for (int k = 0; k < 128; ++k) {
      float w0 = wt_o1[(128 + k) * 512 + r], w1 = wt_o1[(128 + k) * 512 + 256 + r];
      float4 a = c14[k * 2], b = c14[k * 2 + 1];
      FMA_8(A0, w0, a, b);
      FMA_8(A1, w1, a, b);
    }
    #pragma unroll
    for (int tt = 0; tt < 8; ++tt) {
      opre1[((size_t)(t0 + tt)) * 512 + r]       = A0[tt];
      opre1[((size_t)(t0 + tt)) * 512 + 256 + r] = A1[tt];
    }
  }
}

// ---------------------------------------------------------------------------
// phaseC: 8 WGs, one per ensemble e. No inter-WG sync; Whh_o in registers.
// Distance-2 prefetch on the opre streams (cover HBM latency vs short step).
// ---------------------------------------------------------------------------
__launch_bounds__(256, 1)
__global__ void phaseC(const float* __restrict__ opre1, const __hip_bfloat16* __restrict__ opre2,
                       const float* __restrict__ Whh_o, const float* __restrict__ out_h0,
                       const float* __restrict__ out_c0, float* __restrict__ oh_g) {
  __shared__ float ohl[128];
  __shared__ float gl[512];
  const int e = blockIdx.x, tid = threadIdx.x;
  const int r0 = tid, r1 = tid + 256;
  float w0[128], w1[128];
  #pragma unroll
  for (int k = 0; k < 128; ++k) w0[k] = Whh_o[r0 * 128 + k];
  #pragma unroll
  for (int k = 0; k < 128; ++k) w1[k] = Whh_o[r1 * 128 + k];
  if (tid < 128) ohl[tid] = out_h0[e * 128 + tid];
  float creg = (tid < 128) ? out_c0[e * 128 + tid] : 0.f;
  __syncthreads();
  float p0a = opre1[r0], p0b = opre1[r1];
  float q0a = __bfloat162float(opre2[(size_t)e * 512 + r0]);
  float q0b = __bfloat162float(opre2[(size_t)e * 512 + r1]);
  float n0a = opre1[512 + r0], n0b = opre1[512 + r1];
  float m0a = __bfloat162float(opre2[(size_t)(8 + e) * 512 + r0]);
  float m0b = __bfloat162float(opre2[(size_t)(8 + e) * 512 + r1]);
  for (int t = 0; t < T_; ++t) {
    float a0 = p0a + q0a, a1 = p0b + q0b;
    p0a = n0a; p0b = n0b; q0a = m0a; q0b = m0b;
    if (t + 2 < T_) {
      n0a = opre1[(size_t)(t + 2) * 512 + r0];
      n0b = opre1[(size_t)(t + 2) * 512 + r1];
      m0a = __bfloat162float(opre2[((size_t)(t + 2) * 8 + e) * 512 + r0]);
      m0b = __bfloat162float(opre2[((size_t)(t + 2) * 8 + e) * 512 + r1]);
    }
    const float4* o4 = (const float4*)ohl;
    #pragma unroll
    for (int kk = 0; kk < 32; ++kk) {
      float4 x = o4[kk];
      a0 = fmaf(w0[kk * 4 + 0], x.x, a0); a0 = fmaf(w0[kk * 4 + 1], x.y, a0);
      a0 = fmaf(w0[kk * 4 + 2], x.z, a0); a0 = fmaf(w0[kk * 4 + 3], x.w, a0);
      a1 = fmaf(w1[kk * 4 + 0], x.x, a1); a1 = fmaf(w1[kk * 4 + 1], x.y, a1);
      a1 = fmaf(w1[kk * 4 + 2], x.z, a1); a1 = fmaf(w1[kk * 4 + 3], x.w, a1);
    }
    gl[r0] = a0; gl[r1] = a1;
    __syncthreads();
    if (tid < 128) {
      float gi = gl[tid], gf = gl[128 + tid], gg = gl[256 + tid], go = gl[384 + tid];
      float c2 = sigm(gf) * creg + sigm(gi) * tanh_(gg);
      float h2 = sigm(go) * tanh_(c2);
      creg = c2;
      ohl[tid] = h2;
      oh_g[(size_t)t * 1024 + e * 128 + tid] = h2;
    }
    __syncthreads();
  }
}

// ---------------------------------------------------------------------------
// phaseD: parallel over t: softmaxes
// ---------------------------------------------------------------------------
__global__ void phaseD(const float* __restrict__ oh_g,
                       const float* __restrict__ Wtar, const float* __restrict__ btar,
                       const float* __restrict__ Wdir, const float* __restrict__ bdir,
                       float* __restrict__ outp) {
  __shared__ float ohl[1024];
  const int t = blockIdx.x, tid = threadIdx.x;  // 64 threads
  for (int idx = tid; idx < 1024; idx += 64) ohl[idx] = oh_g[(size_t)t * 1024 + idx];
  __syncthreads();
  const int f = tid;
  for (int e = 0; e < E_; ++e) {
    float acc = btar[f];
    const float* wr = Wtar + f * 128;
    #pragma unroll 4
    for (int k = 0; k < 128; ++k) acc = fmaf(wr[k], ohl[e * 128 + k], acc);
    float m = acc;
    #pragma unroll
    for (int off = 32; off; off >>= 1) m = fmaxf(m, __shfl_xor(m, off, 64));
    float ex = __expf(acc - m);
    float s = ex;
    #pragma unroll
    for (int off = 32; off; off >>= 1) s += __shfl_xor(s, off, 64);
    outp[((size_t)t * 8 + e) * 64 + f] = ex / s;
  }
  if (tid < 8) {
    int e = tid;
    float d0 = bdir[0], d1 = bdir[1], d2 = bdir[2];
    #pragma unroll 4
    for (int k = 0; k < 128; ++k) {
      float x = ohl[e * 128 + k];
      d0 = fmaf(Wdir[k], x, d0);
      d1 = fmaf(Wdir[128 + k], x, d1);
      d2 = fmaf(Wdir[256 + k], x, d2);
    }
    float m = fmaxf(d0, fmaxf(d1, d2));
    float x0 = __expf(d0 - m), x1 = __expf(d1 - m), x2 = __expf(d2 - m);
    float s = x0 + x1 + x2;
    float* dp = outp + (size_t)T_ * 8 * 64 + ((size_t)t * 8 + e) * 3;
    dp[0] = x0 / s; dp[1] = x1 / s; dp[2] = x2 / s;
  }
}

extern "C" void kernel_launch(void* const* d_in, const int* in_sizes, int n_in,
                              void* d_out, int out_size, void* d_ws, size_t ws_size,
                              hipStream_t stream) {
  (void)in_sizes; (void)n_in; (void)out_size; (void)ws_size;
  const float* feat   = (const float*)d_in[0];
  const float* pre_h0 = (const float*)d_in[1];
  const float* pre_c0 = (const float*)d_in[2];
  const float* out_h0 = (const float*)d_in[3];
  const float* out_c0 = (const float*)d_in[4];
  const float* Wih_p0 = (const float*)d_in[5];
  const float* Whh_p0 = (const float*)d_in[6];
  const float* b_p0   = (const float*)d_in[7];
  const float* Wih_p1 = (const float*)d_in[8];
  const float* Whh_p1 = (const float*)d_in[9];
  const float* b_p1   = (const float*)d_in[10];
  const float* Wfc    = (const float*)d_in[11];
  const float* bfc    = (const float*)d_in[12];
  const float* Wih_c0 = (const float*)d_in[13];
  const float* Whh_c0 = (const float*)d_in[14];
  const float* b_c0   = (const float*)d_in[15];
  const float* Wih_c1 = (const float*)d_in[16];
  const float* Whh_c1 = (const float*)d_in[17];
  const float* b_c1   = (const float*)d_in[18];
  const float* Wih_o  = (const float*)d_in[19];
  const float* Whh_o  = (const float*)d_in[20];
  const float* b_o    = (const float*)d_in[21];
  const float* Wtar   = (const float*)d_in[22];
  const float* btar   = (const float*)d_in[23];
  const float* Wdir   = (const float*)d_in[24];
  const float* bdir   = (const float*)d_in[25];
  float* outp = (float*)d_out;

  float* ws = (float*)d_ws;
  size_t off = 0;
  float* pre_outB = ws + off; off += (size_t)T_ * E_ * 128;
  float* opre1    = ws + off; off += (size_t)T_ * 512;
  float* oh_g     = ws + off; off += (size_t)T_ * E_ * 128;
  float* wt_p0    = ws + off; off += (size_t)448 * 1024;
  float* wt_p1    = ws + off; off += (size_t)512 * 1024;
  float* wt_c0    = ws + off; off += (size_t)256 * 512;
  float* wt_c1    = ws + off; off += (size_t)256 * 512;
  float* wt_o1    = ws + off; off += (size_t)256 * 512;
  float* wt_o2    = ws + off; off += (size_t)192 * 512;
  __hip_bfloat16* opre2 = (__hip_bfloat16*)(ws + off);
  off += (size_t)T_ * E_ * 512 / 2;
  float* h1all  = ws + off; off += (size_t)T_ * 2048;      // plain stream, read by fcK
  float* h0ring = ws + off; off += (size_t)8 * 2048;       // hot 64 KB ring
  float* h1ring = ws + off; off += (size_t)8 * 2048;       // hot 64 KB ring
  int* flags    = (int*)(ws + off);                        // 2 x 64-slot flag rings
  int* flagsA   = flags;
  int* flagsB   = flags + (size_t)64 * 16 * 32;

  initK<<<dim3(1024), dim3(256), 0, stream>>>(
      Wih_p0, Whh_p0, Wih_p1, Whh_p1, Wih_c0, Whh_c0, Wih_c1, Whh_c1, Wih_o,
      wt_p0, wt_p1, wt_c0, wt_c1, wt_o1, wt_o2, flags);
  opre2K<<<dim3(T_), dim3(256), 0, stream>>>(feat, wt_o2, opre2);
  phaseA<<<dim3(32), dim3(256), 0, stream>>>(
      feat, pre_h0, pre_c0, wt_p0, wt_p1, b_p0, b_p1,
      h0ring, h1ring, h1all, flagsA, flagsB);
  fcK<<<dim3(T_), dim3(256), 0, stream>>>(h1all, Wfc, bfc, pre_outB);
  phaseB<<<dim3(T_ / 8), dim3(256), 0, stream>>>(
      pre_outB, wt_c0, wt_c1, b_c0, b_c1, wt_o1, b_o, opre1);
  phaseC<<<dim3(E_), dim3(256), 0, stream>>>(
      opre1, opre2, Whh_o, out_h0, out_c0, oh_g);
  phaseD<<<dim3(T_), dim3(64), 0, stream>>>(oh_g, Wtar, btar, Wdir, bdir, outp);
}

// Round 10
// 30222.787 us; speedup vs baseline: 1.3024x; 1.1137x over previous
//
#include <hip/hip_runtime.h>
#include <hip/hip_bf16.h>

// Sizes from the reference
#define T_   4096
#define E_   8

typedef unsigned long long ull;

__device__ __forceinline__ float sigm(float x)  { return 1.0f / (1.0f + __expf(-x)); }
__device__ __forceinline__ float tanh_(float x) { return 1.0f - 2.0f / (__expf(2.0f * x) + 1.0f); }

__device__ __forceinline__ ull aload64(const ull* p) {
  return __hip_atomic_load(p, __ATOMIC_RELAXED, __HIP_MEMORY_SCOPE_AGENT);
}
__device__ __forceinline__ int aload32(const int* p) {
  return __hip_atomic_load(p, __ATOMIC_RELAXED, __HIP_MEMORY_SCOPE_AGENT);
}
// barrier draining LDS (lgkm) but not vector memory
__device__ __forceinline__ void lbar() {
  asm volatile("s_waitcnt lgkmcnt(0)\n\ts_barrier" ::: "memory");
}

#define FMA_8(ACC, W, VA, VB)                                   \
  ACC[0] = fmaf((W), (VA).x, ACC[0]); ACC[1] = fmaf((W), (VA).y, ACC[1]); \
  ACC[2] = fmaf((W), (VA).z, ACC[2]); ACC[3] = fmaf((W), (VA).w, ACC[3]); \
  ACC[4] = fmaf((W), (VB).x, ACC[4]); ACC[5] = fmaf((W), (VB).y, ACC[5]); \
  ACC[6] = fmaf((W), (VB).z, ACC[6]); ACC[7] = fmaf((W), (VB).w, ACC[7]);

// ---------------------------------------------------------------------------
// initK: K-major packed weight copies + zero the (small) flag rings.
// ---------------------------------------------------------------------------
__global__ void initK(const float* __restrict__ Wih_p0, const float* __restrict__ Whh_p0,
                      const float* __restrict__ Wih_p1, const float* __restrict__ Whh_p1,
                      const float* __restrict__ Wih_c0, const float* __restrict__ Whh_c0,
                      const float* __restrict__ Wih_c1, const float* __restrict__ Whh_c1,
                      const float* __restrict__ Wih_o,
                      float* wt_p0, float* wt_p1, float* wt_c0, float* wt_c1,
                      float* wt_o1, float* wt_o2, int* flags) {
  const int NW = 458752 + 524288 + 131072 + 131072 + 131072 + 98304;
  const int NF = 2 * 64 * 16 * 32;              // two 64-slot flag rings
  const int NTOT = NW + NF;
  const int gsz = gridDim.x * blockDim.x;
  for (int i = blockIdx.x * blockDim.x + threadIdx.x; i < NTOT; i += gsz) {
    int idx = i;
    if (idx < 458752) { int k = idx >> 10, c = idx & 1023;
      int wg = c >> 6, r6 = c & 63, gate = r6 >> 4, jl = r6 & 15;
      int col = gate * 256 + wg * 16 + jl;
      wt_p0[idx] = (k < 192) ? Wih_p0[col * 192 + k] : Whh_p0[col * 256 + (k - 192)]; continue; }
    idx -= 458752;
    if (idx < 524288) { int k = idx >> 10, c = idx & 1023;
      int wg = c >> 6, r6 = c & 63, gate = r6 >> 4, jl = r6 & 15;
      int col = gate * 256 + wg * 16 + jl;
      wt_p1[idx] = (k < 256) ? Wih_p1[col * 256 + k] : Whh_p1[col * 256 + (k - 256)]; continue; }
    idx -= 524288;
    if (idx < 131072) { int k = idx >> 9, r = idx & 511;
      wt_c0[idx] = (k < 128) ? Wih_c0[r * 128 + k] : Whh_c0[r * 128 + (k - 128)]; continue; }
    idx -= 131072;
    if (idx < 131072) { int k = idx >> 9, r = idx & 511;
      wt_c1[idx] = (k < 128) ? Wih_c1[r * 128 + k] : Whh_c1[r * 128 + (k - 128)]; continue; }
    idx -= 131072;
    if (idx < 131072) { int k = idx >> 9, r = idx & 511;
      wt_o1[idx] = Wih_o[r * 448 + k]; continue; }
    idx -= 131072;
    if (idx < 98304) { int k = idx >> 9, r = idx & 511;
      wt_o2[idx] = Wih_o[r * 448 + 256 + k]; continue; }
    idx -= 98304;
    flags[idx] = 0;
  }
}

// ---------------------------------------------------------------------------
// opre2K: parallel over t. opre2[t][e][512] = Wih_o[:,256:448] @ x(t,e)  (bf16)
// ---------------------------------------------------------------------------
__global__ void opre2K(const float* __restrict__ feat, const float* __restrict__ wt_o2,
                       __hip_bfloat16* __restrict__ opre2) {
  __shared__ float xb[192 * 8];
  const int t = blockIdx.x, tid = threadIdx.x;
  const float* ft = feat + (size_t)t * 640;
  for (int idx = tid; idx < 192 * 8; idx += 256) {
    int k = idx >> 3, e = idx & 7;
    xb[idx] = (k < 128) ? ft[k] : ft[128 + e * 64 + (k - 128)];
  }
  __syncthreads();
  const int r = tid;
  float A0[8] = {0,0,0,0,0,0,0,0};
  float A1[8] = {0,0,0,0,0,0,0,0};
  const float4* x4 = (const float4*)xb;
  #pragma unroll 2
  for (int k = 0; k < 192; ++k) {
    float w0 = wt_o2[k * 512 + r];
    float w1 = wt_o2[k * 512 + 256 + r];
    float4 a = x4[k * 2], b = x4[k * 2 + 1];
    FMA_8(A0, w0, a, b);
    FMA_8(A1, w1, a, b);
  }
  #pragma unroll
  for (int e = 0; e < 8; ++e) {
    opre2[((size_t)t * 8 + e) * 512 + r]       = __float2bfloat16(A0[e]);
    opre2[((size_t)t * 8 + e) * 512 + 256 + r] = __float2bfloat16(A1[e]);
  }
}

// ---------------------------------------------------------------------------
// phaseA: 32 WGs. WG 0-15 = G1 (layer0), WG 16-31 = G2 (layer1, trailing).
// LDS-resident weights + ring exchange + value-tagged flag rings (r9).
// r10: G1 merges the xbuf-ready barrier with the detect barrier (polls run
// concurrently with the x(t+1) refill) -> 4 barriers/step; gather loads are
// issued before the x-part compute so the fabric RTT hides under FMAs.
// ---------------------------------------------------------------------------
__launch_bounds__(256, 1)
__global__ void phaseA(const float* __restrict__ feat,
                       const float* __restrict__ pre_h0, const float* __restrict__ pre_c0,
                       const float* __restrict__ wt_p0, const float* __restrict__ wt_p1,
                       const float* __restrict__ b_p0, const float* __restrict__ b_p1,
                       float* __restrict__ h0ring, float* __restrict__ h1ring,
                       float* __restrict__ h1all,
                       int* __restrict__ flagsA, int* __restrict__ flagsB) {
  __shared__ float lds[38912];   // 155,648 B
  const int wg = blockIdx.x, tid = threadIdx.x;
  const int r6 = tid & 63, kq = tid >> 6;
  const int uj = tid >> 3, ue = tid & 7;

  if (wg < 16) {
    // ============================ G1: layer0 ============================
    float* wl   = lds;            // 28672: weights [k][64], k<448
    float* xbuf = lds + 28672;    // 1536: x(t) [k][e]
    float* hsf  = lds + 30208;    // 2048: h0(t-1) [k][e]
    float* gl   = lds + 32256;    // 2048: partials
    for (int idx = tid; idx < 28672; idx += 256)
      wl[idx] = wt_p0[(size_t)(idx >> 6) * 1024 + wg * 64 + (idx & 63)];
    const int j = wg * 16 + uj;
    float creg = 0.f, bi = 0.f, bff = 0.f, bg = 0.f, bo = 0.f;
    if (tid < 128) {
      creg = pre_c0[(ue * 2 + 0) * 256 + j];
      bi = b_p0[j]; bff = b_p0[256 + j]; bg = b_p0[512 + j]; bo = b_p0[768 + j];
    }
    for (int idx = tid; idx < 2048; idx += 256) {
      int k = idx >> 3, e = idx & 7;
      hsf[idx] = pre_h0[(e * 2 + 0) * 256 + k];
    }
    for (int idx = tid; idx < 1536; idx += 256) {
      int k = idx >> 3, e = idx & 7;
      xbuf[idx] = (k < 128) ? feat[k] : feat[128 + e * 64 + (k - 128)];
    }
    __syncthreads();
    float Ax[8] = {0,0,0,0,0,0,0,0};
    {
      const float4* x4 = (const float4*)xbuf;
      #pragma unroll 8
      for (int k = kq * 48; k < kq * 48 + 48; ++k) {
        float w = wl[k * 64 + r6];
        float4 a = x4[k * 2], b = x4[k * 2 + 1];
        FMA_8(Ax, w, a, b);
      }
    }
    for (int t = 0; t < T_; ++t) {
      float px[6];
      if (t + 1 < T_) {
        const float* ft1 = feat + (size_t)(t + 1) * 640;
        #pragma unroll
        for (int i = 0; i < 6; ++i) {
          int idx = tid + i * 256; int k = idx >> 3, e = idx & 7;
          px[i] = (k < 128) ? ft1[k] : ft1[128 + e * 64 + (k - 128)];
        }
      }
      float A[8];
      #pragma unroll
      for (int i = 0; i < 8; ++i) A[i] = Ax[i];
      {  // h-part: k in [192+kq*64, +64), weights from LDS
        const float4* h4 = (const float4*)hsf;
        const int kb = 192 + kq * 64;
        #pragma unroll 8
        for (int k = kb; k < kb + 64; ++k) {
          float w = wl[k * 64 + r6];
          int kk = k - 192;
          float4 a = h4[kk * 2], b = h4[kk * 2 + 1];
          FMA_8(A, w, a, b);
        }
      }
      {
        float4* g4 = (float4*)gl;
        g4[(kq * 64 + r6) * 2]     = make_float4(A[0], A[1], A[2], A[3]);
        g4[(kq * 64 + r6) * 2 + 1] = make_float4(A[4], A[5], A[6], A[7]);
      }
      if (tid >= 240 && t >= 8) {                  // ring back-pressure (pre-satisfied)
        const int* fp = flagsB + ((size_t)((t - 8) & 63) * 16 + (tid - 240)) * 32;
        while (aload32(fp) != t - 7) __builtin_amdgcn_s_sleep(1);
      }
      lbar();                                      // S1: gl ready, backpressure ok
      if (tid < 128) {
        float s0 = 0.f, s1 = 0.f, s2 = 0.f, s3 = 0.f;
        #pragma unroll
        for (int q = 0; q < 4; ++q) {
          s0 += gl[q * 512 + tid];       s1 += gl[q * 512 + 128 + tid];
          s2 += gl[q * 512 + 256 + tid]; s3 += gl[q * 512 + 384 + tid];
        }
        float c2 = sigm(s1 + bff) * creg + sigm(s0 + bi) * tanh_(s2 + bg);
        float h2 = sigm(s3 + bo) * tanh_(c2);
        creg = c2;
        __hip_atomic_store(&h0ring[(size_t)(t & 7) * 2048 + wg * 128 + tid], h2,
                           __ATOMIC_RELAXED, __HIP_MEMORY_SCOPE_AGENT);
      }
      __syncthreads();                             // S2: publish drained (vmcnt0)
      if (tid == 0)
        __hip_atomic_store(&flagsA[((size_t)(t & 63) * 16 + wg) * 32], t + 1,
                           __ATOMIC_RELAXED, __HIP_MEMORY_SCOPE_AGENT);
      if (t + 1 >= T_) break;
      #pragma unroll
      for (int i = 0; i < 6; ++i) xbuf[tid + i * 256] = px[i];
      if (tid < 16) {                              // detect overlaps xbuf refill
        const int* fp = flagsA + ((size_t)(t & 63) * 16 + tid) * 32;
        while (aload32(fp) != t + 1) __builtin_amdgcn_s_sleep(1);
      }
      lbar();                                      // S3: xbuf ready AND all published
      ull v[4];
      {
        const ull* s8 = (const ull*)(h0ring + (size_t)(t & 7) * 2048);
        #pragma unroll
        for (int i = 0; i < 4; ++i) v[i] = aload64(s8 + tid * 4 + i);   // in flight
      }
      #pragma unroll
      for (int i = 0; i < 8; ++i) Ax[i] = 0.f;
      {  // x-part of t+1 (gather RTT hides under these FMAs)
        const float4* x4 = (const float4*)xbuf;
        #pragma unroll 8
        for (int k = kq * 48; k < kq * 48 + 48; ++k) {
          float w = wl[k * 64 + r6];
          float4 a = x4[k * 2], b = x4[k * 2 + 1];
          FMA_8(Ax, w, a, b);
        }
      }
      {
        ull* d8 = (ull*)hsf;
        #pragma unroll
        for (int i = 0; i < 4; ++i) d8[tid * 4 + i] = v[i];
      }
      lbar();                                      // S4: hsf = h0(t)
    }
  } else {
    // ============================ G2: layer1 ============================
    const int wgl = wg - 16;
    float* wl  = lds;             // 32768: weights [k][64], k<512
    float* xh0 = lds + 32768;     // 2048: h0(t) [k][e]
    float* hsf = lds + 34816;     // 2048: h1(t-1) [k][e]
    float* gl  = lds + 36864;     // 2048
    for (int idx = tid; idx < 32768; idx += 256)
      wl[idx] = wt_p1[(size_t)(idx >> 6) * 1024 + wgl * 64 + (idx & 63)];
    const int j = wgl * 16 + uj;
    float creg = 0.f, bi = 0.f, bff = 0.f, bg = 0.f, bo = 0.f;
    if (tid < 128) {
      creg = pre_c0[(ue * 2 + 1) * 256 + j];
      bi = b_p1[j]; bff = b_p1[256 + j]; bg = b_p1[512 + j]; bo = b_p1[768 + j];
    }
    for (int idx = tid; idx < 2048; idx += 256) {
      int k = idx >> 3, e = idx & 7;
      hsf[idx] = pre_h0[(e * 2 + 1) * 256 + k];
    }
    __syncthreads();
    if (tid < 16) {                                // step-0 flags
      const int* fp = flagsA + (size_t)tid * 32;
      while (aload32(fp) != 1) __builtin_amdgcn_s_sleep(1);
    }
    __syncthreads();
    {
      const ull* s8 = (const ull*)h0ring;          // slot 0
      ull* d8 = (ull*)xh0;
      #pragma unroll
      for (int i = 0; i < 4; ++i) d8[tid * 4 + i] = aload64(s8 + tid * 4 + i);
    }
    __syncthreads();
    float Ax[8] = {0,0,0,0,0,0,0,0};
    {
      const float4* x4 = (const float4*)xh0;
      #pragma unroll 8
      for (int k = kq * 64; k < kq * 64 + 64; ++k) {
        float w = wl[k * 64 + r6];
        float4 a = x4[k * 2], b = x4[k * 2 + 1];
        FMA_8(Ax, w, a, b);
      }
    }
    for (int t = 0; t < T_; ++t) {
      float A[8];
      #pragma unroll
      for (int i = 0; i < 8; ++i) A[i] = Ax[i];
      {  // h1-part: k in [256+kq*64, +64), weights from LDS
        const float4* h4 = (const float4*)hsf;
        const int kb = 256 + kq * 64;
        #pragma unroll 8
        for (int k = kb; k < kb + 64; ++k) {
          float w = wl[k * 64 + r6];
          int kk = k - 256;
          float4 a = h4[kk * 2], b = h4[kk * 2 + 1];
          FMA_8(A, w, a, b);
        }
      }
      {
        float4* g4 = (float4*)gl;
        g4[(kq * 64 + r6) * 2]     = make_float4(A[0], A[1], A[2], A[3]);
        g4[(kq * 64 + r6) * 2 + 1] = make_float4(A[4], A[5], A[6], A[7]);
      }
      lbar();                                      // S1
      if (tid < 128) {
        float s0 = 0.f, s1 = 0.f, s2 = 0.f, s3 = 0.f;
        #pragma unroll
        for (int q = 0; q < 4; ++q) {
          s0 += gl[q * 512 + tid];       s1 += gl[q * 512 + 128 + tid];
          s2 += gl[q * 512 + 256 + tid]; s3 += gl[q * 512 + 384 + tid];
        }
        float c2 = sigm(s1 + bff) * creg + sigm(s0 + bi) * tanh_(s2 + bg);
        float h2 = sigm(s3 + bo) * tanh_(c2);
        creg = c2;
        __hip_atomic_store(&h1ring[(size_t)(t & 7) * 2048 + wgl * 128 + tid], h2,
                           __ATOMIC_RELAXED, __HIP_MEMORY_SCOPE_AGENT);
        h1all[(size_t)t * 2048 + wgl * 128 + tid] = h2;   // plain stream for fcK
      }
      __syncthreads();                             // S2: publish drained
      if (tid == 0)
        __hip_atomic_store(&flagsB[((size_t)(t & 63) * 16 + wgl) * 32], t + 1,
                           __ATOMIC_RELAXED, __HIP_MEMORY_SCOPE_AGENT);
      if (t + 1 >= T_) break;
      if (tid < 32) {                              // combined detect
        const int* fp = (tid < 16)
            ? flagsA + ((size_t)((t + 1) & 63) * 16 + tid) * 32
            : flagsB + ((size_t)(t & 63) * 16 + (tid - 16)) * 32;
        const int want = (tid < 16) ? t + 2 : t + 1;
        while (aload32(fp) != want) __builtin_amdgcn_s_sleep(1);
      }
      lbar();                                      // S3: both ready
      {                                            // both gathers back-to-back
        const ull* s0p = (const ull*)(h0ring + (size_t)((t + 1) & 7) * 2048);
        const ull* s1p = (const ull*)(h1ring + (size_t)(t & 7) * 2048);
        ull v0[4], v1[4];
        #pragma unroll
        for (int i = 0; i < 4; ++i) v0[i] = aload64(s0p + tid * 4 + i);
        #pragma unroll
        for (int i = 0; i < 4; ++i) v1[i] = aload64(s1p + tid * 4 + i);
        ull* d0 = (ull*)xh0; ull* d1 = (ull*)hsf;
        #pragma unroll
        for (int i = 0; i < 4; ++i) { d0[tid * 4 + i] = v0[i]; d1[tid * 4 + i] = v1[i]; }
      }
      lbar();                                      // S4: xh0=h0(t+1), hsf=h1(t)
      #pragma unroll
      for (int i = 0; i < 8; ++i) Ax[i] = 0.f;
      {  // h0-part of t+1
        const float4* x4 = (const float4*)xh0;
        #pragma unroll 8
        for (int k = kq * 64; k < kq * 64 + 64; ++k) {
          float w = wl[k * 64 + r6];
          float4 a = x4[k * 2], b = x4[k * 2 + 1];
          FMA_8(Ax, w, a, b);
        }
      }
    }
  }
}

// ---------------------------------------------------------------------------
// fcK: parallel over t. pre_out[t][e][c] = leaky(Wfc @ h1all[t] + bfc)
// ---------------------------------------------------------------------------
__global__ void fcK(const float* __restrict__ h1all, const float* __restrict__ Wfc,
                    const float* __restrict__ bfc, float* __restrict__ pre_out) {
  __shared__ float hl[2048];
  const int t = blockIdx.x, tid = threadIdx.x;
  for (int idx = tid; idx < 2048; idx += 256) hl[idx] = h1all[(size_t)t * 2048 + idx];
  __syncthreads();
  const int c = tid >> 1, half = tid & 1;
  float b = bfc[c];
  float acc[4] = {b, b, b, b};
  const float4* h4 = (const float4*)hl;
  const float* wrow = Wfc + c * 256;
  #pragma unroll 4
  for (int k = 0; k < 256; ++k) {
    float w = wrow[k];
    float4 x = h4[k * 2 + half];
    acc[0] = fmaf(w, x.x, acc[0]); acc[1] = fmaf(w, x.y, acc[1]);
    acc[2] = fmaf(w, x.z, acc[2]); acc[3] = fmaf(w, x.w, acc[3]);
  }
  #pragma unroll
  for (int i = 0; i < 4; ++i) {
    int e = half * 4 + i;
    float v = acc[i];
    v = (v > 0.f) ? v : 0.05f * v;
    pre_out[((size_t)t * 8 + e) * 128 + c] = v;
  }
}

// ---------------------------------------------------------------------------
// comm cell for phase B
// ---------------------------------------------------------------------------
__device__ __forceinline__ void comm_cell(
    const float* __restrict__ wt, const float* __restrict__ bias,
    const float* xin, float* hL, float* cL, float* glb, float* hout,
    float alpha, int tid) {
  const int r = tid;
  float A0[8] = {0,0,0,0,0,0,0,0};
  float A1[8] = {0,0,0,0,0,0,0,0};
  const float4* x4 = (const float4*)xin;
  #pragma unroll 2
  for (int k = 0; k < 128; ++k) {
    float w0 = wt[k * 512 + r];
    float w1 = wt[k * 512 + 256 + r];
    float4 a = x4[k * 2], b = x4[k * 2 + 1];
    FMA_8(A0, w0, a, b);
    FMA_8(A1, w1, a, b);
  }
  const float4* h4 = (const float4*)hL;
  #pragma unroll 2
  for (int k = 0; k < 128; ++k) {
    float w0 = wt[(128 + k) * 512 + r];
    float w1 = wt[(128 + k) * 512 + 256 + r];
    float4 a = h4[k * 2], b = h4[k * 2 + 1];
    FMA_8(A0, w0, a, b);
    FMA_8(A1, w1, a, b);
  }
  {
    float4* g4 = (float4*)glb;
    g4[r * 2]             = make_float4(A0[0], A0[1], A0[2], A0[3]);
    g4[r * 2 + 1]         = make_float4(A0[4], A0[5], A0[6], A0[7]);
    g4[(256 + r) * 2]     = make_float4(A1[0], A1[1], A1[2], A1[3]);
    g4[(256 + r) * 2 + 1] = make_float4(A1[4], A1[5], A1[6], A1[7]);
  }
  __syncthreads();
  for (int idx = tid; idx < 1024; idx += 256) {
    int jj = idx >> 3, tt = idx & 7;
    float gi = glb[jj * 8 + tt]         + bias[jj];
    float gf = glb[(128 + jj) * 8 + tt] + bias[128 + jj];
    float gg = glb[(256 + jj) * 8 + tt] + bias[256 + jj];
    float go = glb[(384 + jj) * 8 + tt] + bias[384 + jj];
    float cold = cL[idx], hold = hL[idx];
    float c2 = sigm(gf) * cold + sigm(gi) * tanh_(gg);
    float h2 = sigm(go) * tanh_(c2);
    float hb = fmaf(alpha, h2 - hold, hold);
    float cb = fmaf(alpha, c2 - cold, cold);
    hL[idx] = hb; cL[idx] = cb;
    if (hout) hout[idx] = hb;
  }
  __syncthreads();
}

// ---------------------------------------------------------------------------
// phaseB: parallel over t (8 timesteps / WG); emits opre1 (incl. b_o)
// r10: 4 blocks/CU (4 x 40960 B = 160 KiB exactly; VGPR 52 is no constraint)
// ---------------------------------------------------------------------------
__launch_bounds__(256, 4)
__global__ void phaseB(const float* __restrict__ pre_out,
                       const float* __restrict__ wt_c0, const float* __restrict__ wt_c1,
                       const float* __restrict__ b_c0, const float* __restrict__ b_c1,
                       const float* __restrict__ wt_o1, const float* __restrict__ b_o,
                       float* __restrict__ opre1) {
  __shared__ float pol[128 * 8];
  __shared__ float ch0[128 * 8], cc0[128 * 8], ch1[128 * 8], cc1[128 * 8];
  __shared__ float h0b[128 * 8];
  __shared__ float glb[512 * 8];
  const int wg = blockIdx.x, tid = threadIdx.x;
  const int t0 = wg * 8;
  for (int idx = tid; idx < 1024; idx += 256) { ch0[idx]=0.f; cc0[idx]=0.f; ch1[idx]=0.f; cc1[idx]=0.f; }
  __syncthreads();
  float alpha = 1.0f;
  for (int rd = 0; rd < 3; ++rd) {
    for (int e = 0; e < E_; ++e) {
      for (int idx = tid; idx < 1024; idx += 256) {
        int tt = idx >> 7, k = idx & 127;
        pol[k * 8 + tt] = pre_out[(((size_t)(t0 + tt)) * 8 + e) * 128 + k];
      }
      __syncthreads();
      comm_cell(wt_c0, b_c0, pol, ch0, cc0, glb, h0b, alpha, tid);
      comm_cell(wt_c1, b_c1, h0b, ch1, cc1, glb, nullptr, alpha, tid);
    }
    alpha *= 0.333f;
  }
  {
    const int r = tid;
    float A0[8], A1[8];
    #pragma unroll
    for (int tt = 0; tt < 8; ++tt) { A0[tt] = b_o[r]; A1[tt] = b_o[256 + r]; }
    const float4* c04 = (const float4*)cc0;
    const float4* c14 = (const float4*)cc1;
    #pragma unroll 2
    for (int k = 0; k < 128; ++k) {
      float w0 = wt_o1[k * 512 + r], w1 = wt_o1[k * 512 + 256 + r];
      float4 a = c04[k * 2], b = c04[k * 2 + 1];
      FMA_8(A0, w0, a, b);
      FMA_8(A1, w1, a, b);
    }
    #pragma unroll 2
    for (int k = 0; k < 128; ++k) {
      float w0 = wt_o1[(128 + k) * 512 + r], w1 = wt_o1[(128 + k) * 512 + 256 + r];
      float4 a = c14[k * 2], b = c14[k * 2 + 1];
      FMA_8(A0, w0, a, b);
      FMA_8(A1, w1, a, b);
    }
    #pragma unroll
    for (int tt = 0; tt < 8; ++tt) {
      opre1[((size_t)(t0 + tt)) * 512 + r]       = A0[tt];
      opre1[((size_t)(t0 + tt)) * 512 + 256 + r] = A1[tt];
    }
  }
}

// ---------------------------------------------------------------------------
// phaseC: 8 WGs x 512 threads, one per ensemble e. No inter-WG sync.
// r10: ONE row per thread -> 128 weight floats fit in registers for real
// (r9's 2-row variant needed 256 and the compiler re-loaded from L2 every
// step: VGPR_Count=144 proved the spill). Two accumulators halve the chain.
// ---------------------------------------------------------------------------
__launch_bounds__(512, 1)
__global__ void phaseC(const float* __restrict__ opre1, const __hip_bfloat16* __restrict__ opre2,
                       const float* __restrict__ Whh_o, const float* __restrict__ out_h0,
                       const float* __restrict__ out_c0, float* __restrict__ oh_g) {
  __shared__ float ohl[128];
  __shared__ float gl[512];
  const int e = blockIdx.x, tid = threadIdx.x;   // tid = row r in [0,512)
  float w[128];
  #pragma unroll
  for (int k = 0; k < 128; ++k) w[k] = Whh_o[tid * 128 + k];
  if (tid < 128) ohl[tid] = out_h0[e * 128 + tid];
  float creg = (tid < 128) ? out_c0[e * 128 + tid] : 0.f;
  __syncthreads();
  float pa = opre1[tid];
  float qa = __bfloat162float(opre2[(size_t)e * 512 + tid]);
  float na = opre1[512 + tid];
  float ma = __bfloat162float(opre2[(size_t)(8 + e) * 512 + tid]);
  for (int t = 0; t < T_; ++t) {
    float a0 = pa + qa, a1 = 0.f;
    pa = na; qa = ma;
    if (t + 2 < T_) {
      na = opre1[(size_t)(t + 2) * 512 + tid];
      ma = __bfloat162float(opre2[((size_t)(t + 2) * 8 + e) * 512 + tid]);
    }
    const float4* o4 = (const float4*)ohl;
    #pragma unroll
    for (int kk = 0; kk < 16; ++kk) {
      float4 x = o4[2 * kk], y = o4[2 * kk + 1];
      a0 = fmaf(w[kk * 8 + 0], x.x, a0); a0 = fmaf(w[kk * 8 + 1], x.y, a0);
      a0 = fmaf(w[kk * 8 + 2], x.z, a0); a0 = fmaf(w[kk * 8 + 3], x.w, a0);
      a1 = fmaf(w[kk * 8 + 4], y.x, a1); a1 = fmaf(w[kk * 8 + 5], y.y, a1);
      a1 = fmaf(w[kk * 8 + 6], y.z, a1); a1 = fmaf(w[kk * 8 + 7], y.w, a1);
    }
    gl[tid] = a0 + a1;
    __syncthreads();
    if (tid < 128) {
      float gi = gl[tid], gf = gl[128 + tid], gg = gl[256 + tid], go = gl[384 + tid];
      float c2 = sigm(gf) * creg + sigm(gi) * tanh_(gg);
      float h2 = sigm(go) * tanh_(c2);
      creg = c2;
      ohl[tid] = h2;
      oh_g[(size_t)t * 1024 + e * 128 + tid] = h2;
    }
    __syncthreads();
  }
}

// ---------------------------------------------------------------------------
// phaseD: parallel over t: softmaxes
// ---------------------------------------------------------------------------
__global__ void phaseD(const float* __restrict__ oh_g,
                       const float* __restrict__ Wtar, const float* __restrict__ btar,
                       const float* __restrict__ Wdir, const float* __restrict__ bdir,
                       float* __restrict__ outp) {
  __shared__ float ohl[1024];
  const int t = blockIdx.x, tid = threadIdx.x;  // 64 threads
  for (int idx = tid; idx < 1024; idx += 64) ohl[idx] = oh_g[(size_t)t * 1024 + idx];
  __syncthreads();
  const int f = tid;
  for (int e = 0; e < E_; ++e) {
    float acc = btar[f];
    const float* wr = Wtar + f * 128;
    #pragma unroll 4
    for (int k = 0; k < 128; ++k) acc = fmaf(wr[k], ohl[e * 128 + k], acc);
    float m = acc;
    #pragma unroll
    for (int off = 32; off; off >>= 1) m = fmaxf(m, __shfl_xor(m, off, 64));
    float ex = __expf(acc - m);
    float s = ex;
    #pragma unroll
    for (int off = 32; off; off >>= 1) s += __shfl_xor(s, off, 64);
    outp[((size_t)t * 8 + e) * 64 + f] = ex / s;
  }
  if (tid < 8) {
    int e = tid;
    float d0 = bdir[0], d1 = bdir[1], d2 = bdir[2];
    #pragma unroll 4
    for (int k = 0; k < 128; ++k) {
      float x = ohl[e * 128 + k];
      d0 = fmaf(Wdir[k], x, d0);
      d1 = fmaf(Wdir[128 + k], x, d1);
      d2 = fmaf(Wdir[256 + k], x, d2);
    }
    float m = fmaxf(d0, fmaxf(d1, d2));
    float x0 = __expf(d0 - m), x1 = __expf(d1 - m), x2 = __expf(d2 - m);
    float s = x0 + x1 + x2;
    float* dp = outp + (size_t)T_ * 8 * 64 + ((size_t)t * 8 + e) * 3;
    dp[0] = x0 / s; dp[1] = x1 / s; dp[2] = x2 / s;
  }
}

extern "C" void kernel_launch(void* const* d_in, const int* in_sizes, int n_in,
                              void* d_out, int out_size, void* d_ws, size_t ws_size,
                              hipStream_t stream) {
  (void)in_sizes; (void)n_in; (void)out_size; (void)ws_size;
  const float* feat   = (const float*)d_in[0];
  const float* pre_h0 = (const float*)d_in[1];
  const float* pre_c0 = (const float*)d_in[2];
  const float* out_h0 = (const float*)d_in[3];
  const float* out_c0 = (const float*)d_in[4];
  const float* Wih_p0 = (const float*)d_in[5];
  const float* Whh_p0 = (const float*)d_in[6];
  const float* b_p0   = (const float*)d_in[7];
  const float* Wih_p1 = (const float*)d_in[8];
  const float* Whh_p1 = (const float*)d_in[9];
  const float* b_p1   = (const float*)d_in[10];
  const float* Wfc    = (const float*)d_in[11];
  const float* bfc    = (const float*)d_in[12];
  const float* Wih_c0 = (const float*)d_in[13];
  const float* Whh_c0 = (const float*)d_in[14];
  const float* b_c0   = (const float*)d_in[15];
  const float* Wih_c1 = (const float*)d_in[16];
  const float* Whh_c1 = (const float*)d_in[17];
  const float* b_c1   = (const float*)d_in[18];
  const float* Wih_o  = (const float*)d_in[19];
  const float* Whh_o  = (const float*)d_in[20];
  const float* b_o    = (const float*)d_in[21];
  const float* Wtar   = (const float*)d_in[22];
  const float* btar   = (const float*)d_in[23];
  const float* Wdir   = (const float*)d_in[24];
  const float* bdir   = (const float*)d_in[25];
  float* outp = (float*)d_out;

  float* ws = (float*)d_ws;
  size_t off = 0;
  float* pre_outB = ws + off; off += (size_t)T_ * E_ * 128;
  float* opre1    = ws + off; off += (size_t)T_ * 512;
  float* oh_g     = ws + off; off += (size_t)T_ * E_ * 128;
  float* wt_p0    = ws + off; off += (size_t)448 * 1024;
  float* wt_p1    = ws + off; off += (size_t)512 * 1024;
  float* wt_c0    = ws + off; off += (size_t)256 * 512;
  float* wt_c1    = ws + off; off += (size_t)256 * 512;
  float* wt_o1    = ws + off; off += (size_t)256 * 512;
  float* wt_o2    = ws + off; off += (size_t)192 * 512;
  __hip_bfloat16* opre2 = (__hip_bfloat16*)(ws + off);
  off += (size_t)T_ * E_ * 512 / 2;
  float* h1all  = ws + off; off += (size_t)T_ * 2048;      // plain stream, read by fcK
  float* h0ring = ws + off; off += (size_t)8 * 2048;       // hot 64 KB ring
  float* h1ring = ws + off; off += (size_t)8 * 2048;       // hot 64 KB ring
  int* flags    = (int*)(ws + off);                        // 2 x 64-slot flag rings
  int* flagsA   = flags;
  int* flagsB   = flags + (size_t)64 * 16 * 32;

  initK<<<dim3(1024), dim3(256), 0, stream>>>(
      Wih_p0, Whh_p0, Wih_p1, Whh_p1, Wih_c0, Whh_c0, Wih_c1, Whh_c1, Wih_o,
      wt_p0, wt_p1, wt_c0, wt_c1, wt_o1, wt_o2, flags);
  opre2K<<<dim3(T_), dim3(256), 0, stream>>>(feat, wt_o2, opre2);
  phaseA<<<dim3(32), dim3(256), 0, stream>>>(
      feat, pre_h0, pre_c0, wt_p0, wt_p1, b_p0, b_p1,
      h0ring, h1ring, h1all, flagsA, flagsB);
  fcK<<<dim3(T_), dim3(256), 0, stream>>>(h1all, Wfc, bfc, pre_outB);
  phaseB<<<dim3(T_ / 8), dim3(256), 0, stream>>>(
      pre_outB, wt_c0, wt_c1, b_c0, b_c1, wt_o1, b_o, opre1);
  phaseC<<<dim3(E_), dim3(512), 0, stream>>>(
      opre1, opre2, Whh_o, out_h0, out_c0, oh_g);
  phaseD<<<dim3(T_), dim3(64), 0, stream>>>(oh_g, Wtar, btar, Wdir, bdir, outp);
}

// Round 11
// 23731.636 us; speedup vs baseline: 1.6587x; 1.2735x over previous
//
#include <hip/hip_runtime.h>
#include <hip/hip_bf16.h>

// Sizes from the reference
#define T_   4096
#define E_   8
#define NCON 208   // consumer blocks in the mega-kernel

typedef unsigned long long ull;

__device__ __forceinline__ float sigm(float x)  { return 1.0f / (1.0f + __expf(-x)); }
__device__ __forceinline__ float tanh_(float x) { return 1.0f - 2.0f / (__expf(2.0f * x) + 1.0f); }

__device__ __forceinline__ ull aload64(const ull* p) {
  return __hip_atomic_load(p, __ATOMIC_RELAXED, __HIP_MEMORY_SCOPE_AGENT);
}
__device__ __forceinline__ int aload32(const int* p) {
  return __hip_atomic_load(p, __ATOMIC_RELAXED, __HIP_MEMORY_SCOPE_AGENT);
}
__device__ __forceinline__ float aloadf(const float* p) {
  return __hip_atomic_load(p, __ATOMIC_RELAXED, __HIP_MEMORY_SCOPE_AGENT);
}
// barrier draining LDS (lgkm) but not vector memory
__device__ __forceinline__ void lbar() {
  asm volatile("s_waitcnt lgkmcnt(0)\n\ts_barrier" ::: "memory");
}

#define FMA_8(ACC, W, VA, VB)                                   \
  ACC[0] = fmaf((W), (VA).x, ACC[0]); ACC[1] = fmaf((W), (VA).y, ACC[1]); \
  ACC[2] = fmaf((W), (VA).z, ACC[2]); ACC[3] = fmaf((W), (VA).w, ACC[3]); \
  ACC[4] = fmaf((W), (VB).x, ACC[4]); ACC[5] = fmaf((W), (VB).y, ACC[5]); \
  ACC[6] = fmaf((W), (VB).z, ACC[6]); ACC[7] = fmaf((W), (VB).w, ACC[7]);

// ---------------------------------------------------------------------------
// initK: K-major packed weight copies + zero flag rings and flagC.
// ---------------------------------------------------------------------------
__global__ void initK(const float* __restrict__ Wih_p0, const float* __restrict__ Whh_p0,
                      const float* __restrict__ Wih_p1, const float* __restrict__ Whh_p1,
                      const float* __restrict__ Wih_c0, const float* __restrict__ Whh_c0,
                      const float* __restrict__ Wih_c1, const float* __restrict__ Whh_c1,
                      const float* __restrict__ Wih_o,
                      float* wt_p0, float* wt_p1, float* wt_c0, float* wt_c1,
                      float* wt_o1, float* wt_o2, int* flags) {
  const int NW = 458752 + 524288 + 131072 + 131072 + 131072 + 98304;
  const int NF = 2 * 64 * 16 * 32 + 512 * 32;   // flag rings + flagC
  const int NTOT = NW + NF;
  const int gsz = gridDim.x * blockDim.x;
  for (int i = blockIdx.x * blockDim.x + threadIdx.x; i < NTOT; i += gsz) {
    int idx = i;
    if (idx < 458752) { int k = idx >> 10, c = idx & 1023;
      int wg = c >> 6, r6 = c & 63, gate = r6 >> 4, jl = r6 & 15;
      int col = gate * 256 + wg * 16 + jl;
      wt_p0[idx] = (k < 192) ? Wih_p0[col * 192 + k] : Whh_p0[col * 256 + (k - 192)]; continue; }
    idx -= 458752;
    if (idx < 524288) { int k = idx >> 10, c = idx & 1023;
      int wg = c >> 6, r6 = c & 63, gate = r6 >> 4, jl = r6 & 15;
      int col = gate * 256 + wg * 16 + jl;
      wt_p1[idx] = (k < 256) ? Wih_p1[col * 256 + k] : Whh_p1[col * 256 + (k - 256)]; continue; }
    idx -= 524288;
    if (idx < 131072) { int k = idx >> 9, r = idx & 511;
      wt_c0[idx] = (k < 128) ? Wih_c0[r * 128 + k] : Whh_c0[r * 128 + (k - 128)]; continue; }
    idx -= 131072;
    if (idx < 131072) { int k = idx >> 9, r = idx & 511;
      wt_c1[idx] = (k < 128) ? Wih_c1[r * 128 + k] : Whh_c1[r * 128 + (k - 128)]; continue; }
    idx -= 131072;
    if (idx < 131072) { int k = idx >> 9, r = idx & 511;
      wt_o1[idx] = Wih_o[r * 448 + k]; continue; }
    idx -= 131072;
    if (idx < 98304) { int k = idx >> 9, r = idx & 511;
      wt_o2[idx] = Wih_o[r * 448 + 256 + k]; continue; }
    idx -= 98304;
    flags[idx] = 0;
  }
}

// ---------------------------------------------------------------------------
// opre2K: parallel over t. opre2[t][e][512] = Wih_o[:,256:448] @ x(t,e)  (bf16)
// ---------------------------------------------------------------------------
__global__ void opre2K(const float* __restrict__ feat, const float* __restrict__ wt_o2,
                       __hip_bfloat16* __restrict__ opre2) {
  __shared__ float xb[192 * 8];
  const int t = blockIdx.x, tid = threadIdx.x;
  const float* ft = feat + (size_t)t * 640;
  for (int idx = tid; idx < 192 * 8; idx += 256) {
    int k = idx >> 3, e = idx & 7;
    xb[idx] = (k < 128) ? ft[k] : ft[128 + e * 64 + (k - 128)];
  }
  __syncthreads();
  const int r = tid;
  float A0[8] = {0,0,0,0,0,0,0,0};
  float A1[8] = {0,0,0,0,0,0,0,0};
  const float4* x4 = (const float4*)xb;
  #pragma unroll 2
  for (int k = 0; k < 192; ++k) {
    float w0 = wt_o2[k * 512 + r];
    float w1 = wt_o2[k * 512 + 256 + r];
    float4 a = x4[k * 2], b = x4[k * 2 + 1];
    FMA_8(A0, w0, a, b);
    FMA_8(A1, w1, a, b);
  }
  #pragma unroll
  for (int e = 0; e < 8; ++e) {
    opre2[((size_t)t * 8 + e) * 512 + r]       = __float2bfloat16(A0[e]);
    opre2[((size_t)t * 8 + e) * 512 + 256 + r] = __float2bfloat16(A1[e]);
  }
}

// ---------------------------------------------------------------------------
// comm cell (unchanged math)
// ---------------------------------------------------------------------------
__device__ __forceinline__ void comm_cell(
    const float* __restrict__ wt, const float* __restrict__ bias,
    const float* xin, float* hL, float* cL, float* glb, float* hout,
    float alpha, int tid) {
  const int r = tid;
  float A0[8] = {0,0,0,0,0,0,0,0};
  float A1[8] = {0,0,0,0,0,0,0,0};
  const float4* x4 = (const float4*)xin;
  #pragma unroll 2
  for (int k = 0; k < 128; ++k) {
    float w0 = wt[k * 512 + r];
    float w1 = wt[k * 512 + 256 + r];
    float4 a = x4[k * 2], b = x4[k * 2 + 1];
    FMA_8(A0, w0, a, b);
    FMA_8(A1, w1, a, b);
  }
  const float4* h4 = (const float4*)hL;
  #pragma unroll 2
  for (int k = 0; k < 128; ++k) {
    float w0 = wt[(128 + k) * 512 + r];
    float w1 = wt[(128 + k) * 512 + 256 + r];
    float4 a = h4[k * 2], b = h4[k * 2 + 1];
    FMA_8(A0, w0, a, b);
    FMA_8(A1, w1, a, b);
  }
  {
    float4* g4 = (float4*)glb;
    g4[r * 2]             = make_float4(A0[0], A0[1], A0[2], A0[3]);
    g4[r * 2 + 1]         = make_float4(A0[4], A0[5], A0[6], A0[7]);
    g4[(256 + r) * 2]     = make_float4(A1[0], A1[1], A1[2], A1[3]);
    g4[(256 + r) * 2 + 1] = make_float4(A1[4], A1[5], A1[6], A1[7]);
  }
  __syncthreads();
  for (int idx = tid; idx < 1024; idx += 256) {
    int jj = idx >> 3, tt = idx & 7;
    float gi = glb[jj * 8 + tt]         + bias[jj];
    float gf = glb[(128 + jj) * 8 + tt] + bias[128 + jj];
    float gg = glb[(256 + jj) * 8 + tt] + bias[256 + jj];
    float go = glb[(384 + jj) * 8 + tt] + bias[384 + jj];
    float cold = cL[idx], hold = hL[idx];
    float c2 = sigm(gf) * cold + sigm(gi) * tanh_(gg);
    float h2 = sigm(go) * tanh_(c2);
    float hb = fmaf(alpha, h2 - hold, hold);
    float cb = fmaf(alpha, c2 - cold, cold);
    hL[idx] = hb; cL[idx] = cb;
    if (hout) hout[idx] = hb;
  }
  __syncthreads();
}

// ---------------------------------------------------------------------------
// MEGA kernel: 248 blocks, 256 thr, 155648 B LDS => 1 block/CU => all 248
// resident simultaneously (248 <= 256 CUs), so the producer/consumer flag
// waits are deadlock-free regardless of dispatch order.
//   blocks 0-31 : phaseA (r10 structure; h1all store is agent-atomic)
//   blocks 32-39: phaseC per-e (rows 0-255 weights in regs, 256-511 in LDS
//                 [k][256] lane-consecutive), gated on flagC per 8-t chunk
//   blocks 40-  : consumers: fused fc+comm for chunks of 8 ts, gated on
//                 flagsB; emit opre1 (atomic) + flagC
// ---------------------------------------------------------------------------
__launch_bounds__(256, 1)
__global__ void megaK(const float* __restrict__ feat,
                      const float* __restrict__ pre_h0, const float* __restrict__ pre_c0,
                      const float* __restrict__ wt_p0, const float* __restrict__ wt_p1,
                      const float* __restrict__ b_p0, const float* __restrict__ b_p1,
                      float* __restrict__ h0ring, float* __restrict__ h1ring,
                      float* __restrict__ h1all,
                      int* __restrict__ flagsA, int* __restrict__ flagsB,
                      const float* __restrict__ Wfc, const float* __restrict__ bfc,
                      const float* __restrict__ wt_c0, const float* __restrict__ wt_c1,
                      const float* __restrict__ b_c0, const float* __restrict__ b_c1,
                      const float* __restrict__ wt_o1, const float* __restrict__ b_o,
                      float* __restrict__ opre1, int* __restrict__ flagC,
                      const __hip_bfloat16* __restrict__ opre2,
                      const float* __restrict__ Whh_o, const float* __restrict__ out_h0,
                      const float* __restrict__ out_c0, float* __restrict__ oh_g) {
  __shared__ float lds[38912];   // 155,648 B
  const int wg = blockIdx.x, tid = threadIdx.x;
  const int r6 = tid & 63, kq = tid >> 6;
  const int uj = tid >> 3, ue = tid & 7;

  if (wg < 16) {
    // ============================ G1: layer0 ============================
    float* wl   = lds;            // 28672: weights [k][64], k<448
    float* xbuf = lds + 28672;    // 1536
    float* hsf  = lds + 30208;    // 2048
    float* gl   = lds + 32256;    // 2048
    for (int idx = tid; idx < 28672; idx += 256)
      wl[idx] = wt_p0[(size_t)(idx >> 6) * 1024 + wg * 64 + (idx & 63)];
    const int j = wg * 16 + uj;
    float creg = 0.f, bi = 0.f, bff = 0.f, bg = 0.f, bo = 0.f;
    if (tid < 128) {
      creg = pre_c0[(ue * 2 + 0) * 256 + j];
      bi = b_p0[j]; bff = b_p0[256 + j]; bg = b_p0[512 + j]; bo = b_p0[768 + j];
    }
    for (int idx = tid; idx < 2048; idx += 256) {
      int k = idx >> 3, e = idx & 7;
      hsf[idx] = pre_h0[(e * 2 + 0) * 256 + k];
    }
    for (int idx = tid; idx < 1536; idx += 256) {
      int k = idx >> 3, e = idx & 7;
      xbuf[idx] = (k < 128) ? feat[k] : feat[128 + e * 64 + (k - 128)];
    }
    __syncthreads();
    float Ax[8] = {0,0,0,0,0,0,0,0};
    {
      const float4* x4 = (const float4*)xbuf;
      #pragma unroll 8
      for (int k = kq * 48; k < kq * 48 + 48; ++k) {
        float w = wl[k * 64 + r6];
        float4 a = x4[k * 2], b = x4[k * 2 + 1];
        FMA_8(Ax, w, a, b);
      }
    }
    for (int t = 0; t < T_; ++t) {
      float px[6];
      if (t + 1 < T_) {
        const float* ft1 = feat + (size_t)(t + 1) * 640;
        #pragma unroll
        for (int i = 0; i < 6; ++i) {
          int idx = tid + i * 256; int k = idx >> 3, e = idx & 7;
          px[i] = (k < 128) ? ft1[k] : ft1[128 + e * 64 + (k - 128)];
        }
      }
      float A[8];
      #pragma unroll
      for (int i = 0; i < 8; ++i) A[i] = Ax[i];
      {
        const float4* h4 = (const float4*)hsf;
        const int kb = 192 + kq * 64;
        #pragma unroll 8
        for (int k = kb; k < kb + 64; ++k) {
          float w = wl[k * 64 + r6];
          int kk = k - 192;
          float4 a = h4[kk * 2], b = h4[kk * 2 + 1];
          FMA_8(A, w, a, b);
        }
      }
      {
        float4* g4 = (float4*)gl;
        g4[(kq * 64 + r6) * 2]     = make_float4(A[0], A[1], A[2], A[3]);
        g4[(kq * 64 + r6) * 2 + 1] = make_float4(A[4], A[5], A[6], A[7]);
      }
      if (tid >= 240 && t >= 8) {                  // ring back-pressure
        const int* fp = flagsB + ((size_t)((t - 8) & 63) * 16 + (tid - 240)) * 32;
        while (aload32(fp) < t - 7) __builtin_amdgcn_s_sleep(1);
      }
      lbar();                                      // S1
      if (tid < 128) {
        float s0 = 0.f, s1 = 0.f, s2 = 0.f, s3 = 0.f;
        #pragma unroll
        for (int q = 0; q < 4; ++q) {
          s0 += gl[q * 512 + tid];       s1 += gl[q * 512 + 128 + tid];
          s2 += gl[q * 512 + 256 + tid]; s3 += gl[q * 512 + 384 + tid];
        }
        float c2 = sigm(s1 + bff) * creg + sigm(s0 + bi) * tanh_(s2 + bg);
        float h2 = sigm(s3 + bo) * tanh_(c2);
        creg = c2;
        __hip_atomic_store(&h0ring[(size_t)(t & 7) * 2048 + wg * 128 + tid], h2,
                           __ATOMIC_RELAXED, __HIP_MEMORY_SCOPE_AGENT);
      }
      __syncthreads();                             // S2: publish drained
      if (tid == 0)
        __hip_atomic_store(&flagsA[((size_t)(t & 63) * 16 + wg) * 32], t + 1,
                           __ATOMIC_RELAXED, __HIP_MEMORY_SCOPE_AGENT);
      if (t + 1 >= T_) break;
      #pragma unroll
      for (int i = 0; i < 6; ++i) xbuf[tid + i * 256] = px[i];
      if (tid < 16) {                              // detect overlaps refill
        const int* fp = flagsA + ((size_t)(t & 63) * 16 + tid) * 32;
        while (aload32(fp) < t + 1) __builtin_amdgcn_s_sleep(1);
      }
      lbar();                                      // S3
      ull v[4];
      {
        const ull* s8 = (const ull*)(h0ring + (size_t)(t & 7) * 2048);
        #pragma unroll
        for (int i = 0; i < 4; ++i) v[i] = aload64(s8 + tid * 4 + i);
      }
      #pragma unroll
      for (int i = 0; i < 8; ++i) Ax[i] = 0.f;
      {
        const float4* x4 = (const float4*)xbuf;
        #pragma unroll 8
        for (int k = kq * 48; k < kq * 48 + 48; ++k) {
          float w = wl[k * 64 + r6];
          float4 a = x4[k * 2], b = x4[k * 2 + 1];
          FMA_8(Ax, w, a, b);
        }
      }
      {
        ull* d8 = (ull*)hsf;
        #pragma unroll
        for (int i = 0; i < 4; ++i) d8[tid * 4 + i] = v[i];
      }
      lbar();                                      // S4
    }
  } else if (wg < 32) {
    // ============================ G2: layer1 ============================
    const int wgl = wg - 16;
    float* wl  = lds;             // 32768
    float* xh0 = lds + 32768;     // 2048
    float* hsf = lds + 34816;     // 2048
    float* gl  = lds + 36864;     // 2048
    for (int idx = tid; idx < 32768; idx += 256)
      wl[idx] = wt_p1[(size_t)(idx >> 6) * 1024 + wgl * 64 + (idx & 63)];
    const int j = wgl * 16 + uj;
    float creg = 0.f, bi = 0.f, bff = 0.f, bg = 0.f, bo = 0.f;
    if (tid < 128) {
      creg = pre_c0[(ue * 2 + 1) * 256 + j];
      bi = b_p1[j]; bff = b_p1[256 + j]; bg = b_p1[512 + j]; bo = b_p1[768 + j];
    }
    for (int idx = tid; idx < 2048; idx += 256) {
      int k = idx >> 3, e = idx & 7;
      hsf[idx] = pre_h0[(e * 2 + 1) * 256 + k];
    }
    __syncthreads();
    if (tid < 16) {
      const int* fp = flagsA + (size_t)tid * 32;
      while (aload32(fp) < 1) __builtin_amdgcn_s_sleep(1);
    }
    __syncthreads();
    {
      const ull* s8 = (const ull*)h0ring;
      ull* d8 = (ull*)xh0;
      #pragma unroll
      for (int i = 0; i < 4; ++i) d8[tid * 4 + i] = aload64(s8 + tid * 4 + i);
    }
    __syncthreads();
    float Ax[8] = {0,0,0,0,0,0,0,0};
    {
      const float4* x4 = (const float4*)xh0;
      #pragma unroll 8
      for (int k = kq * 64; k < kq * 64 + 64; ++k) {
        float w = wl[k * 64 + r6];
        float4 a = x4[k * 2], b = x4[k * 2 + 1];
        FMA_8(Ax, w, a, b);
      }
    }
    for (int t = 0; t < T_; ++t) {
      float A[8];
      #pragma unroll
      for (int i = 0; i < 8; ++i) A[i] = Ax[i];
      {
        const float4* h4 = (const float4*)hsf;
        const int kb = 256 + kq * 64;
        #pragma unroll 8
        for (int k = kb; k < kb + 64; ++k) {
          float w = wl[k * 64 + r6];
          int kk = k - 256;
          float4 a = h4[kk * 2], b = h4[kk * 2 + 1];
          FMA_8(A, w, a, b);
        }
      }
      {
        float4* g4 = (float4*)gl;
        g4[(kq * 64 + r6) * 2]     = make_float4(A[0], A[1], A[2], A[3]);
        g4[(kq * 64 + r6) * 2 + 1] = make_float4(A[4], A[5], A[6], A[7]);
      }
      lbar();                                      // S1
      if (tid < 128) {
        float s0 = 0.f, s1 = 0.f, s2 = 0.f, s3 = 0.f;
        #pragma unroll
        for (int q = 0; q < 4; ++q) {
          s0 += gl[q * 512 + tid];       s1 += gl[q * 512 + 128 + tid];
          s2 += gl[q * 512 + 256 + tid]; s3 += gl[q * 512 + 384 + tid];
        }
        float c2 = sigm(s1 + bff) * creg + sigm(s0 + bi) * tanh_(s2 + bg);
        float h2 = sigm(s3 + bo) * tanh_(c2);
        creg = c2;
        __hip_atomic_store(&h1ring[(size_t)(t & 7) * 2048 + wgl * 128 + tid], h2,
                           __ATOMIC_RELAXED, __HIP_MEMORY_SCOPE_AGENT);
        __hip_atomic_store(&h1all[(size_t)t * 2048 + wgl * 128 + tid], h2,
                           __ATOMIC_RELAXED, __HIP_MEMORY_SCOPE_AGENT);
      }
      __syncthreads();                             // S2: publish drained
      if (tid == 0)
        __hip_atomic_store(&flagsB[((size_t)(t & 63) * 16 + wgl) * 32], t + 1,
                           __ATOMIC_RELAXED, __HIP_MEMORY_SCOPE_AGENT);
      if (t + 1 >= T_) break;
      if (tid < 32) {                              // combined detect
        const int* fp = (tid < 16)
            ? flagsA + ((size_t)((t + 1) & 63) * 16 + tid) * 32
            : flagsB + ((size_t)(t & 63) * 16 + (tid - 16)) * 32;
        const int want = (tid < 16) ? t + 2 : t + 1;
        while (aload32(fp) < want) __builtin_amdgcn_s_sleep(1);
      }
      lbar();                                      // S3
      {
        const ull* s0p = (const ull*)(h0ring + (size_t)((t + 1) & 7) * 2048);
        const ull* s1p = (const ull*)(h1ring + (size_t)(t & 7) * 2048);
        ull v0[4], v1[4];
        #pragma unroll
        for (int i = 0; i < 4; ++i) v0[i] = aload64(s0p + tid * 4 + i);
        #pragma unroll
        for (int i = 0; i < 4; ++i) v1[i] = aload64(s1p + tid * 4 + i);
        ull* d0 = (ull*)xh0; ull* d1 = (ull*)hsf;
        #pragma unroll
        for (int i = 0; i < 4; ++i) { d0[tid * 4 + i] = v0[i]; d1[tid * 4 + i] = v1[i]; }
      }
      lbar();                                      // S4
      #pragma unroll
      for (int i = 0; i < 8; ++i) Ax[i] = 0.f;
      {
        const float4* x4 = (const float4*)xh0;
        #pragma unroll 8
        for (int k = kq * 64; k < kq * 64 + 64; ++k) {
          float w = wl[k * 64 + r6];
          float4 a = x4[k * 2], b = x4[k * 2 + 1];
          FMA_8(Ax, w, a, b);
        }
      }
    }
  } else if (wg < 40) {
    // ============================ phaseC (per e) ============================
    const int e = wg - 32;
    float* wlds = lds;            // [k][256] rows 256-511: 32768 floats
    float* ohl  = lds + 32768;    // 128
    float* gl   = lds + 32896;    // 512
    for (int idx = tid; idx < 32768; idx += 256) {
      int k = idx >> 8, rr = idx & 255;
      wlds[idx] = Whh_o[(256 + rr) * 128 + k];
    }
    float w[128];
    #pragma unroll
    for (int k = 0; k < 128; ++k) w[k] = Whh_o[tid * 128 + k];
    if (tid < 128) ohl[tid] = out_h0[e * 128 + tid];
    float creg = (tid < 128) ? out_c0[e * 128 + tid] : 0.f;
    __syncthreads();
    if (tid == 0) { while (aload32(&flagC[0]) == 0) __builtin_amdgcn_s_sleep(4); }
    __syncthreads();
    const int r0 = tid, r1 = tid + 256;
    float pa = aloadf(&opre1[r0]), pb = aloadf(&opre1[r1]);
    float qa = __bfloat162float(opre2[(size_t)e * 512 + r0]);
    float qb = __bfloat162float(opre2[(size_t)e * 512 + r1]);
    float na = aloadf(&opre1[512 + r0]), nb = aloadf(&opre1[512 + r1]);
    float ma = __bfloat162float(opre2[(size_t)(8 + e) * 512 + r0]);
    float mb = __bfloat162float(opre2[(size_t)(8 + e) * 512 + r1]);
    for (int t = 0; t < T_; ++t) {
      float a0 = pa + qa, a1 = pb + qb;
      pa = na; pb = nb; qa = ma; qb = mb;
      if ((t & 7) == 6 && t + 2 < T_) {            // next chunk ready?
        if (tid == 0) { while (aload32(&flagC[((t + 2) >> 3) * 32]) == 0) __builtin_amdgcn_s_sleep(4); }
        __syncthreads();
      }
      if (t + 2 < T_) {
        na = aloadf(&opre1[(size_t)(t + 2) * 512 + r0]);
        nb = aloadf(&opre1[(size_t)(t + 2) * 512 + r1]);
        ma = __bfloat162float(opre2[((size_t)(t + 2) * 8 + e) * 512 + r0]);
        mb = __bfloat162float(opre2[((size_t)(t + 2) * 8 + e) * 512 + r1]);
      }
      const float4* o4 = (const float4*)ohl;
      #pragma unroll
      for (int kk = 0; kk < 32; ++kk) {
        float4 x = o4[kk];
        a0 = fmaf(w[kk * 4 + 0], x.x, a0); a0 = fmaf(w[kk * 4 + 1], x.y, a0);
        a0 = fmaf(w[kk * 4 + 2], x.z, a0); a0 = fmaf(w[kk * 4 + 3], x.w, a0);
        a1 = fmaf(wlds[(kk * 4 + 0) * 256 + tid], x.x, a1);
        a1 = fmaf(wlds[(kk * 4 + 1) * 256 + tid], x.y, a1);
        a1 = fmaf(wlds[(kk * 4 + 2) * 256 + tid], x.z, a1);
        a1 = fmaf(wlds[(kk * 4 + 3) * 256 + tid], x.w, a1);
      }
      gl[r0] = a0; gl[r1] = a1;
      __syncthreads();
      if (tid < 128) {
        float gi = gl[tid], gf = gl[128 + tid], gg = gl[256 + tid], go = gl[384 + tid];
        float c2 = sigm(gf) * creg + sigm(gi) * tanh_(gg);
        float h2 = sigm(go) * tanh_(c2);
        creg = c2;
        ohl[tid] = h2;
        oh_g[(size_t)t * 1024 + e * 128 + tid] = h2;
      }
      __syncthreads();
    }
  } else {
    // ==================== consumers: fused fc + comm ====================
    const int cb = wg - 40;
    float* h1c    = lds;          // 16384
    float* polAll = lds + 16384;  // 8192
    float* ch0 = lds + 24576; float* cc0 = lds + 25600;
    float* ch1 = lds + 26624; float* cc1 = lds + 27648;
    float* h0b = lds + 28672;     // 1024
    float* glb = lds + 29696;     // 4096
    for (int chunk = cb; chunk < 512; chunk += NCON) {
      const int t0 = chunk * 8;
      if (tid < 16) {
        const int* fp = flagsB + ((size_t)((t0 + 7) & 63) * 16 + tid) * 32;
        while (aload32(fp) < t0 + 8) __builtin_amdgcn_s_sleep(4);
      }
      __syncthreads();
      {
        const ull* src = (const ull*)(h1all + (size_t)t0 * 2048);
        ull* dst = (ull*)h1c;
        for (int i = tid; i < 8192; i += 256) dst[i] = aload64(src + i);
      }
      __syncthreads();
      {  // fc for 8 ts -> polAll[e][c*8+tt]
        const int c = tid >> 1, half = tid & 1;
        const float bv = bfc[c];
        const float* wrow = Wfc + c * 256;
        for (int tt = 0; tt < 8; ++tt) {
          float a0 = bv, a1 = bv, a2 = bv, a3 = bv;
          const float4* h4 = (const float4*)(h1c + tt * 2048);
          #pragma unroll 4
          for (int k = 0; k < 256; ++k) {
            float wv = wrow[k];
            float4 x = h4[k * 2 + half];
            a0 = fmaf(wv, x.x, a0); a1 = fmaf(wv, x.y, a1);
            a2 = fmaf(wv, x.z, a2); a3 = fmaf(wv, x.w, a3);
          }
          float vv[4] = {a0, a1, a2, a3};
          #pragma unroll
          for (int i = 0; i < 4; ++i) {
            float v = vv[i];
            v = (v > 0.f) ? v : 0.05f * v;
            polAll[(half * 4 + i) * 1024 + c * 8 + tt] = v;
          }
        }
      }
      for (int idx = tid; idx < 1024; idx += 256) { ch0[idx]=0.f; cc0[idx]=0.f; ch1[idx]=0.f; cc1[idx]=0.f; }
      __syncthreads();
      float alpha = 1.0f;
      for (int rd = 0; rd < 3; ++rd) {
        for (int e = 0; e < E_; ++e) {
          comm_cell(wt_c0, b_c0, polAll + e * 1024, ch0, cc0, glb, h0b, alpha, tid);
          comm_cell(wt_c1, b_c1, h0b, ch1, cc1, glb, nullptr, alpha, tid);
        }
        alpha *= 0.333f;
      }
      {  // opre1 epilogue (atomic stores for intra-kernel visibility)
        const int r = tid;
        float A0[8], A1[8];
        #pragma unroll
        for (int tt = 0; tt < 8; ++tt) { A0[tt] = b_o[r]; A1[tt] = b_o[256 + r]; }
        const float4* c04 = (const float4*)cc0;
        const float4* c14 = (const float4*)cc1;
        #pragma unroll 2
        for (int k = 0; k < 128; ++k) {
          float w0 = wt_o1[k * 512 + r], w1 = wt_o1[k * 512 + 256 + r];
          float4 a = c04[k * 2], b = c04[k * 2 + 1];
          FMA_8(A0, w0, a, b);
          FMA_8(A1, w1, a, b);
        }
        #pragma unroll 2
        for (int k = 0; k < 128; ++k) {
          float w0 = wt_o1[(128 + k) * 512 + r], w1 = wt_o1[(128 + k) * 512 + 256 + r];
          float4 a = c14[k * 2], b = c14[k * 2 + 1];
          FMA_8(A0, w0, a, b);
          FMA_8(A1, w1, a, b);
        }
        #pragma unroll
        for (int tt = 0; tt < 8; ++tt) {
          __hip_atomic_store(&opre1[((size_t)(t0 + tt)) * 512 + r], A0[tt],
                             __ATOMIC_RELAXED, __HIP_MEMORY_SCOPE_AGENT);
          __hip_atomic_store(&opre1[((size_t)(t0 + tt)) * 512 + 256 + r], A1[tt],
                             __ATOMIC_RELAXED, __HIP_MEMORY_SCOPE_AGENT);
        }
      }
      __syncthreads();                             // drain opre1 (vmcnt0)
      if (tid == 0)
        __hip_atomic_store(&flagC[chunk * 32], 1, __ATOMIC_RELAXED, __HIP_MEMORY_SCOPE_AGENT);
      __syncthreads();
    }
  }
}

// ---------------------------------------------------------------------------
// phaseD: parallel over t: softmaxes
// ---------------------------------------------------------------------------
__global__ void phaseD(const float* __restrict__ oh_g,
                       const float* __restrict__ Wtar, const float* __restrict__ btar,
                       const float* __restrict__ Wdir, const float* __restrict__ bdir,
                       float* __restrict__ outp) {
  __shared__ float ohl[1024];
  const int t = blockIdx.x, tid = threadIdx.x;  // 64 threads
  for (int idx = tid; idx < 1024; idx += 64) ohl[idx] = oh_g[(size_t)t * 1024 + idx];
  __syncthreads();
  const int f = tid;
  for (int e = 0; e < E_; ++e) {
    float acc = btar[f];
    const float* wr = Wtar + f * 128;
    #pragma unroll 4
    for (int k = 0; k < 128; ++k) acc = fmaf(wr[k], ohl[e * 128 + k], acc);
    float m = acc;
    #pragma unroll
    for (int off = 32; off; off >>= 1) m = fmaxf(m, __shfl_xor(m, off, 64));
    float ex = __expf(acc - m);
    float s = ex;
    #pragma unroll
    for (int off = 32; off; off >>= 1) s += __shfl_xor(s, off, 64);
    outp[((size_t)t * 8 + e) * 64 + f] = ex / s;
  }
  if (tid < 8) {
    int e = tid;
    float d0 = bdir[0], d1 = bdir[1], d2 = bdir[2];
    #pragma unroll 4
    for (int k = 0; k < 128; ++k) {
      float x = ohl[e * 128 + k];
      d0 = fmaf(Wdir[k], x, d0);
      d1 = fmaf(Wdir[128 + k], x, d1);
      d2 = fmaf(Wdir[256 + k], x, d2);
    }
    float m = fmaxf(d0, fmaxf(d1, d2));
    float x0 = __expf(d0 - m), x1 = __expf(d1 - m), x2 = __expf(d2 - m);
    float s = x0 + x1 + x2;
    float* dp = outp + (size_t)T_ * 8 * 64 + ((size_t)t * 8 + e) * 3;
    dp[0] = x0 / s; dp[1] = x1 / s; dp[2] = x2 / s;
  }
}

extern "C" void kernel_launch(void* const* d_in, const int* in_sizes, int n_in,
                              void* d_out, int out_size, void* d_ws, size_t ws_size,
                              hipStream_t stream) {
  (void)in_sizes; (void)n_in; (void)out_size; (void)ws_size;
  const float* feat   = (const float*)d_in[0];
  const float* pre_h0 = (const float*)d_in[1];
  const float* pre_c0 = (const float*)d_in[2];
  const float* out_h0 = (const float*)d_in[3];
  const float* out_c0 = (const float*)d_in[4];
  const float* Wih_p0 = (const float*)d_in[5];
  const float* Whh_p0 = (const float*)d_in[6];
  const float* b_p0   = (const float*)d_in[7];
  const float* Wih_p1 = (const float*)d_in[8];
  const float* Whh_p1 = (const float*)d_in[9];
  const float* b_p1   = (const float*)d_in[10];
  const float* Wfc    = (const float*)d_in[11];
  const float* bfc    = (const float*)d_in[12];
  const float* Wih_c0 = (const float*)d_in[13];
  const float* Whh_c0 = (const float*)d_in[14];
  const float* b_c0   = (const float*)d_in[15];
  const float* Wih_c1 = (const float*)d_in[16];
  const float* Whh_c1 = (const float*)d_in[17];
  const float* b_c1   = (const float*)d_in[18];
  const float* Wih_o  = (const float*)d_in[19];
  const float* Whh_o  = (const float*)d_in[20];
  const float* b_o    = (const float*)d_in[21];
  const float* Wtar   = (const float*)d_in[22];
  const float* btar   = (const float*)d_in[23];
  const float* Wdir   = (const float*)d_in[24];
  const float* bdir   = (const float*)d_in[25];
  float* outp = (float*)d_out;

  float* ws = (float*)d_ws;
  size_t off = 0;
  float* opre1    = ws + off; off += (size_t)T_ * 512;
  float* oh_g     = ws + off; off += (size_t)T_ * E_ * 128;
  float* wt_p0    = ws + off; off += (size_t)448 * 1024;
  float* wt_p1    = ws + off; off += (size_t)512 * 1024;
  float* wt_c0    = ws + off; off += (size_t)256 * 512;
  float* wt_c1    = ws + off; off += (size_t)256 * 512;
  float* wt_o1    = ws + off; off += (size_t)256 * 512;
  float* wt_o2    = ws + off; off += (size_t)192 * 512;
  __hip_bfloat16* opre2 = (__hip_bfloat16*)(ws + off);
  off += (size_t)T_ * E_ * 512 / 2;
  float* h1all  = ws + off; off += (size_t)T_ * 2048;
  float* h0ring = ws + off; off += (size_t)8 * 2048;
  float* h1ring = ws + off; off += (size_t)8 * 2048;
  int* flags    = (int*)(ws + off);          // flagsA + flagsB + flagC
  int* flagsA   = flags;
  int* flagsB   = flags + (size_t)64 * 16 * 32;
  int* flagC    = flags + (size_t)2 * 64 * 16 * 32;   // 512 slots x 32 stride

  initK<<<dim3(1024), dim3(256), 0, stream>>>(
      Wih_p0, Whh_p0, Wih_p1, Whh_p1, Wih_c0, Whh_c0, Wih_c1, Whh_c1, Wih_o,
      wt_p0, wt_p1, wt_c0, wt_c1, wt_o1, wt_o2, flags);
  opre2K<<<dim3(T_), dim3(256), 0, stream>>>(feat, wt_o2, opre2);
  megaK<<<dim3(32 + 8 + NCON), dim3(256), 0, stream>>>(
      feat, pre_h0, pre_c0, wt_p0, wt_p1, b_p0, b_p1,
      h0ring, h1ring, h1all, flagsA, flagsB,
      Wfc, bfc, wt_c0, wt_c1, b_c0, b_c1, wt_o1, b_o, opre1, flagC,
      opre2, Whh_o, out_h0, out_c0, oh_g);
  phaseD<<<dim3(T_), dim3(64), 0, stream>>>(oh_g, Wtar, btar, Wdir, bdir, outp);
}